// Round 1
// baseline (2498.847 us; speedup 1.0000x reference)
//
#include <hip/hip_runtime.h>
#include <cstdint>

typedef unsigned long long u64;

#define NBOX 3000
#define CCH  256
#define KDIM 12544   // 256*49
#define NCLS 20
#define NW   47      // ceil(3000/64) u64 words

// ---------------- workspace layout (float offsets) ----------------
// featT3 (HWC)      : 128*128*256 = 4,194,304
// featT4            : 64*64*256   = 1,048,576
// featT5            : 32*32*256   =   262,144
// A (3072 x 12544)  : 38,535,168   (rows padded to 3072; pad rows read poison, harmless)
// h1 (3072 x 1024)  : 3,145,728
// h2 (3072 x 1024)  : 3,145,728
// scores / classesF / maxv / obox / area / ord / ssort / sup / rem
static constexpr size_t OFF_FT3  = 0;
static constexpr size_t OFF_FT4  = 4194304;
static constexpr size_t OFF_FT5  = 5242880;
static constexpr size_t OFF_A    = 5505024;
static constexpr size_t OFF_H1   = 44040192;
static constexpr size_t OFF_H2   = 47185920;
static constexpr size_t OFF_SC   = 50331648;
static constexpr size_t OFF_CL   = 50334720;
static constexpr size_t OFF_MAXV = 50337792;
static constexpr size_t OFF_OBOX = 50337856;
static constexpr size_t OFF_AREA = 50349888;
static constexpr size_t OFF_ORD  = 50352896;   // int
static constexpr size_t OFF_SSORT= 50355968;
static constexpr size_t OFF_SUP  = 50359040;   // u64[3000*47]  (byte off %8==0)
static constexpr size_t OFF_REM  = 50641040;   // u64[47]
// total ~50.65M floats ~= 203 MB of d_ws

// ---------------- CHW -> HWC transpose (one block per pixel) ----------------
__global__ __launch_bounds__(256) void k_transpose(const float* __restrict__ in,
                                                   float* __restrict__ out, int HW)
{
    int p = blockIdx.x;
    int c = threadIdx.x;
    out[(size_t)p * CCH + c] = in[(size_t)c * HW + p];
}

// ---------------- ROI align: block = (sample s, box m), thread = channel ----------------
__global__ __launch_bounds__(256) void k_roialign(
    const float* __restrict__ fT3, const float* __restrict__ fT4, const float* __restrict__ fT5,
    const float* __restrict__ pr3, const float* __restrict__ pr4, const float* __restrict__ pr5,
    float* __restrict__ A)
{
    int s = blockIdx.x;              // 0..48  (sy*7+sx)
    int m = blockIdx.y;              // 0..2999
    int sy = s / 7, sx = s - sy * 7;
    int lvl = m / 1000, n = m - lvl * 1000;
    const float* pr; const float* fT; int W; float inv;
    if (lvl == 0)      { pr = pr3; fT = fT3; W = 128; inv = 0.125f;   }
    else if (lvl == 1) { pr = pr4; fT = fT4; W = 64;  inv = 0.0625f;  }
    else               { pr = pr5; fT = fT5; W = 32;  inv = 0.03125f; }

    float x1 = __fmul_rn(pr[n*4+0], inv);
    float y1 = __fmul_rn(pr[n*4+1], inv);
    float x2 = __fmul_rn(pr[n*4+2], inv);
    float y2 = __fmul_rn(pr[n*4+3], inv);
    float bx = __fdiv_rn(__fadd_rn((float)sx, 0.5f), 7.0f);
    float by = __fdiv_rn(__fadd_rn((float)sy, 0.5f), 7.0f);
    float xs = __fsub_rn(__fadd_rn(x1, __fmul_rn(bx, __fsub_rn(x2, x1))), 0.5f);
    float ys = __fsub_rn(__fadd_rn(y1, __fmul_rn(by, __fsub_rn(y2, y1))), 0.5f);
    float x0f = floorf(xs), y0f = floorf(ys);
    float wx = __fsub_rn(xs, x0f), wy = __fsub_rn(ys, y0f);
    int x0i = min(max((int)x0f, 0), W - 1);
    int x1i = min(x0i + 1, W - 1);
    int y0i = min(max((int)y0f, 0), W - 1);
    int y1i = min(y0i + 1, W - 1);
    const float* b00 = fT + (size_t)(y0i * W + x0i) * CCH;
    const float* b01 = fT + (size_t)(y0i * W + x1i) * CCH;
    const float* b10 = fT + (size_t)(y1i * W + x0i) * CCH;
    const float* b11 = fT + (size_t)(y1i * W + x1i) * CCH;
    int c = threadIdx.x;
    float v00 = b00[c], v01 = b01[c], v10 = b10[c], v11 = b11[c];
    float omwx = __fsub_rn(1.0f, wx), omwy = __fsub_rn(1.0f, wy);
    float top = __fadd_rn(__fmul_rn(omwx, v00), __fmul_rn(wx, v01));
    float bot = __fadd_rn(__fmul_rn(omwx, v10), __fmul_rn(wx, v11));
    float val = __fadd_rn(__fmul_rn(omwy, top), __fmul_rn(wy, bot));
    // A layout: k' = s*256 + c  (GEMM permutes w1 rows to compensate)
    A[(size_t)m * KDIM + (size_t)s * CCH + c] = val;
}

// ---------------- fp32 tiled GEMM 64x64, BK=16, + bias + relu ----------------
// PERM=1: B row = (k&255)*49 + (k>>8)   (w1 row permutation for A's k'=s*256+c layout)
template<int PERM>
__global__ __launch_bounds__(256) void k_gemm_relu(
    const float* __restrict__ A, const float* __restrict__ B,
    const float* __restrict__ bias, float* __restrict__ C,
    int M, int K, int lda)
{
    __shared__ float As[16][68];   // +4 pad
    __shared__ float Bs[16][64];
    int bm = blockIdx.x * 64;
    int bn = blockIdx.y * 64;
    int tid = threadIdx.x;
    int tm = tid & 15, tn = tid >> 4;
    int lam = tid >> 2, lak = (tid & 3) << 2;   // A-tile: row, k-quad
    int lbk = tid >> 4, lbn = (tid & 15) << 2;  // B-tile: k-row, n-quad
    float acc[4][4];
    #pragma unroll
    for (int i = 0; i < 4; ++i)
        #pragma unroll
        for (int j = 0; j < 4; ++j) acc[i][j] = 0.f;

    for (int k0 = 0; k0 < K; k0 += 16) {
        float4 av = *(const float4*)(A + (size_t)(bm + lam) * lda + (k0 + lak));
        int krow = k0 + lbk;
        int brow = PERM ? ((krow & 255) * 49 + (krow >> 8)) : krow;
        float4 bv = *(const float4*)(B + (size_t)brow * 1024 + (bn + lbn));
        As[lak + 0][lam] = av.x;
        As[lak + 1][lam] = av.y;
        As[lak + 2][lam] = av.z;
        As[lak + 3][lam] = av.w;
        *(float4*)&Bs[lbk][lbn] = bv;
        __syncthreads();
        #pragma unroll
        for (int kk = 0; kk < 16; ++kk) {
            float ar[4], br[4];
            *(float4*)ar = *(const float4*)&As[kk][tm << 2];
            *(float4*)br = *(const float4*)&Bs[kk][tn << 2];
            #pragma unroll
            for (int i = 0; i < 4; ++i)
                #pragma unroll
                for (int j = 0; j < 4; ++j)
                    acc[i][j] = fmaf(ar[i], br[j], acc[i][j]);
        }
        __syncthreads();
    }
    #pragma unroll
    for (int i = 0; i < 4; ++i) {
        int m = bm + (tm << 2) + i;
        if (m < M) {
            float o[4];
            #pragma unroll
            for (int j = 0; j < 4; ++j)
                o[j] = fmaxf(acc[i][j] + bias[bn + (tn << 2) + j], 0.f);
            *(float4*)(C + (size_t)m * 1024 + bn + (tn << 2)) = *(float4*)o;
        }
    }
}

// ---------------- classifier head: logits -> sigmoid -> max/argmax ----------------
__global__ __launch_bounds__(128) void k_head(
    const float* __restrict__ h2, const float* __restrict__ wc, const float* __restrict__ bc,
    float* __restrict__ scores, float* __restrict__ classesF)
{
    __shared__ float hrow[1024];
    __shared__ float probs[NCLS];
    int m = blockIdx.x, tid = threadIdx.x;
    #pragma unroll
    for (int i = 0; i < 2; ++i) {
        int idx = (tid + i * 128) << 2;
        *(float4*)&hrow[idx] = *(const float4*)(h2 + (size_t)m * 1024 + idx);
    }
    __syncthreads();
    if (tid < NCLS) {
        float acc = 0.f;
        for (int k = 0; k < 1024; ++k) acc = fmaf(hrow[k], wc[k * NCLS + tid], acc);
        float logit = __fadd_rn(acc, bc[tid]);
        probs[tid] = __fdiv_rn(1.0f, __fadd_rn(1.0f, expf(-logit)));
    }
    __syncthreads();
    if (tid == 0) {
        float best = -1.0f; int bi = 0;
        for (int n2 = 0; n2 < NCLS; ++n2) {
            float p = probs[n2];
            if (p > best) { best = p; bi = n2; }   // strict > == first-max (argmax semantics)
        }
        scores[m] = best;
        classesF[m] = (float)bi;
    }
}

// ---------------- global max over all box coords ----------------
__global__ __launch_bounds__(1024) void k_boxmax(const float* __restrict__ a,
                                                 const float* __restrict__ b,
                                                 const float* __restrict__ c,
                                                 float* __restrict__ maxv)
{
    __shared__ float red[1024];
    int tid = threadIdx.x;
    float v = -1e30f;
    for (int i = tid; i < 4000; i += 1024) {
        v = fmaxf(v, a[i]); v = fmaxf(v, b[i]); v = fmaxf(v, c[i]);
    }
    red[tid] = v; __syncthreads();
    for (int s = 512; s > 0; s >>= 1) {
        if (tid < s) red[tid] = fmaxf(red[tid], red[tid + s]);
        __syncthreads();
    }
    if (tid == 0) maxv[0] = red[0];
}

// ---------------- per-box class-offset box + area ----------------
__global__ __launch_bounds__(256) void k_prep(
    const float* __restrict__ pr3, const float* __restrict__ pr4, const float* __restrict__ pr5,
    const float* __restrict__ classesF, const float* __restrict__ maxv,
    float* __restrict__ obox, float* __restrict__ area)
{
    int i = blockIdx.x * 256 + threadIdx.x;
    if (i >= NBOX) return;
    int lvl = i / 1000, n = i - lvl * 1000;
    const float* pr = lvl == 0 ? pr3 : (lvl == 1 ? pr4 : pr5);
    float off = __fmul_rn(classesF[i], __fadd_rn(maxv[0], 1.0f));
    float b0 = __fadd_rn(pr[n*4+0], off);
    float b1 = __fadd_rn(pr[n*4+1], off);
    float b2 = __fadd_rn(pr[n*4+2], off);
    float b3 = __fadd_rn(pr[n*4+3], off);
    obox[i*4+0] = b0; obox[i*4+1] = b1; obox[i*4+2] = b2; obox[i*4+3] = b3;
    area[i] = __fmul_rn(fmaxf(__fsub_rn(b2, b0), 0.f), fmaxf(__fsub_rn(b3, b1), 0.f));
}

// ---------------- bitonic argsort (score desc, idx asc == stable argsort(-s)) ----------------
__global__ __launch_bounds__(1024) void k_sort(const float* __restrict__ scores,
                                               int* __restrict__ ord, float* __restrict__ ssort)
{
    __shared__ float ss[4096];
    __shared__ int   si[4096];
    int tid = threadIdx.x;
    for (int t = tid; t < 4096; t += 1024) {
        if (t < NBOX) { ss[t] = scores[t]; si[t] = t; }
        else          { ss[t] = -__builtin_inff(); si[t] = t; }
    }
    __syncthreads();
    for (int k = 2; k <= 4096; k <<= 1) {
        for (int j = k >> 1; j > 0; j >>= 1) {
            for (int t = tid; t < 4096; t += 1024) {
                int l = t ^ j;
                if (l > t) {
                    float st = ss[t], sl = ss[l];
                    int it = si[t], il = si[l];
                    bool up = ((t & k) == 0);
                    bool lLessT = (sl > st) || (sl == st && il < it);  // "less" = earlier in output
                    if (lLessT == up) { ss[t] = sl; ss[l] = st; si[t] = il; si[l] = it; }
                }
            }
            __syncthreads();
        }
    }
    for (int t = tid; t < NBOX; t += 1024) { ord[t] = si[t]; ssort[t] = ss[t]; }
}

// ---------------- suppression bitmask: sup[i][w] bit j = (iou(sorted i, sorted j)>0.5 && j>i) ----------------
__global__ __launch_bounds__(256) void k_sup(
    const int* __restrict__ ord, const float* __restrict__ obox, const float* __restrict__ area,
    u64* __restrict__ sup)
{
    int i = blockIdx.x;
    int w = blockIdx.y * 4 + (threadIdx.x >> 6);  // wave-uniform
    int lane = threadIdx.x & 63;
    if (w >= NW) return;
    int j = (w << 6) + lane;
    bool s = false;
    int oi = ord[i];
    float bi0 = obox[oi*4+0], bi1 = obox[oi*4+1], bi2 = obox[oi*4+2], bi3 = obox[oi*4+3];
    float ai = area[oi];
    if (j > i && j < NBOX) {
        int oj = ord[j];
        float bj0 = obox[oj*4+0], bj1 = obox[oj*4+1], bj2 = obox[oj*4+2], bj3 = obox[oj*4+3];
        float lt0 = fmaxf(bi0, bj0), lt1 = fmaxf(bi1, bj1);
        float rb0 = fminf(bi2, bj2), rb1 = fminf(bi3, bj3);
        float w0 = fmaxf(__fsub_rn(rb0, lt0), 0.f), w1 = fmaxf(__fsub_rn(rb1, lt1), 0.f);
        float inter = __fmul_rn(w0, w1);
        float den = __fadd_rn(__fsub_rn(__fadd_rn(ai, area[oj]), inter), 1e-8f);
        float iou = __fdiv_rn(inter, den);
        s = iou > 0.5f;
    }
    u64 mask = __ballot(s);
    if (lane == 0) sup[(size_t)i * NW + w] = mask;
}

// ---------------- sequential NMS scan over bitmask (1 wave; lane = word) ----------------
__global__ __launch_bounds__(64) void k_nmsseq(
    const float* __restrict__ ssort, const u64* __restrict__ sup, u64* __restrict__ rem)
{
    int l = threadIdx.x;
    u64 r = 0;
    if (l < NW) {
        for (int b = 0; b < 64; ++b) {
            int idx = (l << 6) + b;
            if (idx < NBOX && ssort[idx] >= 0.05f) r |= (1ull << b);
        }
    }
    for (int i = 0; i < NBOX; ++i) {
        int wi = i >> 6;
        unsigned lo = __shfl((unsigned)(r & 0xffffffffull), wi);
        unsigned hi = __shfl((unsigned)(r >> 32), wi);
        u64 wv = ((u64)hi << 32) | lo;
        if ((wv >> (i & 63)) & 1ull) {
            if (l < NW) r &= ~sup[(size_t)i * NW + l];
        }
    }
    if (l < NW) rem[l] = r;
}

// ---------------- final output assembly ----------------
// out: [0,12000) boxes | [12000,15000) classes | [15000,18000) scores | [18000,21000) keep
__global__ __launch_bounds__(256) void k_out(
    const float* __restrict__ pr3, const float* __restrict__ pr4, const float* __restrict__ pr5,
    const float* __restrict__ classesF, const float* __restrict__ scores,
    const int* __restrict__ ord, const u64* __restrict__ rem, float* __restrict__ out)
{
    int t = blockIdx.x * 256 + threadIdx.x;
    if (t >= 21000) return;
    if (t < 12000) {
        int m = t >> 2, j = t & 3;
        int lvl = m / 1000, n = m - lvl * 1000;
        const float* pr = lvl == 0 ? pr3 : (lvl == 1 ? pr4 : pr5);
        out[t] = pr[n*4 + j];
    } else if (t < 15000) {
        out[t] = classesF[t - 12000];
    } else if (t < 18000) {
        out[t] = scores[t - 15000];
    } else {
        int p = t - 18000;                 // sorted position
        int orig = ord[p];
        int bit = (int)((rem[p >> 6] >> (p & 63)) & 1ull);
        out[18000 + orig] = (float)bit;    // scatter: keep[order[p]] = keep_sorted[p]
    }
}

extern "C" void kernel_launch(void* const* d_in, const int* in_sizes, int n_in,
                              void* d_out, int out_size, void* d_ws, size_t ws_size,
                              hipStream_t stream)
{
    const float* p3  = (const float*)d_in[0];
    const float* p4  = (const float*)d_in[1];
    const float* p5  = (const float*)d_in[2];
    const float* pr3 = (const float*)d_in[3];
    const float* pr4 = (const float*)d_in[4];
    const float* pr5 = (const float*)d_in[5];
    const float* w1  = (const float*)d_in[6];
    const float* b1  = (const float*)d_in[7];
    const float* w2  = (const float*)d_in[8];
    const float* b2  = (const float*)d_in[9];
    const float* wc  = (const float*)d_in[10];
    const float* bc  = (const float*)d_in[11];

    float* ws    = (float*)d_ws;
    float* fT3   = ws + OFF_FT3;
    float* fT4   = ws + OFF_FT4;
    float* fT5   = ws + OFF_FT5;
    float* A     = ws + OFF_A;
    float* h1    = ws + OFF_H1;
    float* h2    = ws + OFF_H2;
    float* sc    = ws + OFF_SC;
    float* clf   = ws + OFF_CL;
    float* maxv  = ws + OFF_MAXV;
    float* obox  = ws + OFF_OBOX;
    float* area  = ws + OFF_AREA;
    int*   ord   = (int*)(ws + OFF_ORD);
    float* ssort = ws + OFF_SSORT;
    u64*   sup   = (u64*)(ws + OFF_SUP);
    u64*   rem   = (u64*)(ws + OFF_REM);
    float* out   = (float*)d_out;

    k_transpose<<<128 * 128, 256, 0, stream>>>(p3, fT3, 128 * 128);
    k_transpose<<<64 * 64,   256, 0, stream>>>(p4, fT4, 64 * 64);
    k_transpose<<<32 * 32,   256, 0, stream>>>(p5, fT5, 32 * 32);
    k_roialign<<<dim3(49, NBOX), 256, 0, stream>>>(fT3, fT4, fT5, pr3, pr4, pr5, A);
    k_boxmax<<<1, 1024, 0, stream>>>(pr3, pr4, pr5, maxv);
    k_gemm_relu<1><<<dim3(47, 16), 256, 0, stream>>>(A,  w1, b1, h1, NBOX, KDIM, KDIM);
    k_gemm_relu<0><<<dim3(47, 16), 256, 0, stream>>>(h1, w2, b2, h2, NBOX, 1024, 1024);
    k_head<<<NBOX, 128, 0, stream>>>(h2, wc, bc, sc, clf);
    k_prep<<<12, 256, 0, stream>>>(pr3, pr4, pr5, clf, maxv, obox, area);
    k_sort<<<1, 1024, 0, stream>>>(sc, ord, ssort);
    k_sup<<<dim3(NBOX, 12), 256, 0, stream>>>(ord, obox, area, sup);
    k_nmsseq<<<1, 64, 0, stream>>>(ssort, sup, rem);
    k_out<<<(21000 + 255) / 256, 256, 0, stream>>>(pr3, pr4, pr5, clf, sc, ord, rem, out);
}

// Round 3
// 1919.778 us; speedup vs baseline: 1.3016x; 1.3016x over previous
//
#include <hip/hip_runtime.h>
#include <cstdint>

typedef unsigned long long u64;

#define NBOX 3000
#define CCH  256
#define KDIM 12544   // 256*49
#define NCLS 20
#define NW   47      // ceil(3000/64) u64 words

// ---------------- workspace layout (float offsets) ----------------
static constexpr size_t OFF_FT3  = 0;            // 128*128*256
static constexpr size_t OFF_FT4  = 4194304;      // 64*64*256
static constexpr size_t OFF_FT5  = 5242880;      // 32*32*256
static constexpr size_t OFF_A    = 5505024;      // 3072 x 12544 (pad rows poison; harmless tiny floats)
static constexpr size_t OFF_H1   = 44040192;     // 3072 x 1024
static constexpr size_t OFF_H2   = 47185920;     // 3072 x 1024
static constexpr size_t OFF_SC   = 50331648;
static constexpr size_t OFF_CL   = 50334720;
static constexpr size_t OFF_MAXV = 50337792;
static constexpr size_t OFF_OBOX = 50337856;
static constexpr size_t OFF_AREA = 50349888;
static constexpr size_t OFF_ORD  = 50352896;     // int
static constexpr size_t OFF_SSORT= 50355968;
static constexpr size_t OFF_SUP  = 50359040;     // u64[3000*47]
static constexpr size_t OFF_REM  = 50641040;     // u64[47]
static constexpr size_t OFF_CP   = 50641152;     // 4 x 3072 x 1024 split-K partials
static constexpr size_t OFF_WCT  = 63224064;     // 20 x 1024
// total ~63.25M floats ~= 253 MB of d_ws

// ---------------- CHW -> HWC transpose, LDS-tiled 64x64 ----------------
__global__ __launch_bounds__(256) void k_transpose2(const float* __restrict__ in,
                                                    float* __restrict__ out, int HW)
{
    __shared__ float t[64][65];
    int pb = blockIdx.x * 64;        // pixel base
    int cb = blockIdx.y * 64;        // channel base
    int tid = threadIdx.x;
    int x = tid & 63, y4 = tid >> 6; // 0..3
    #pragma unroll
    for (int i = 0; i < 16; ++i) {
        int cr = y4 + i * 4;
        t[x][cr] = in[(size_t)(cb + cr) * HW + pb + x];
    }
    __syncthreads();
    #pragma unroll
    for (int i = 0; i < 16; ++i) {
        int pr = y4 + i * 4;
        out[(size_t)(pb + pr) * CCH + cb + x] = t[pr][x];
    }
}

// ---------------- ROI align: one block per box, loop 49 samples ----------------
__global__ __launch_bounds__(256) void k_roialign2(
    const float* __restrict__ fT3, const float* __restrict__ fT4, const float* __restrict__ fT5,
    const float* __restrict__ pr3, const float* __restrict__ pr4, const float* __restrict__ pr5,
    float* __restrict__ A)
{
    int m = blockIdx.x;
    int lvl = m / 1000, n = m - lvl * 1000;
    const float* pr; const float* fT; int W; float inv;
    if (lvl == 0)      { pr = pr3; fT = fT3; W = 128; inv = 0.125f;   }
    else if (lvl == 1) { pr = pr4; fT = fT4; W = 64;  inv = 0.0625f;  }
    else               { pr = pr5; fT = fT5; W = 32;  inv = 0.03125f; }

    float x1 = __fmul_rn(pr[n*4+0], inv);
    float y1 = __fmul_rn(pr[n*4+1], inv);
    float x2 = __fmul_rn(pr[n*4+2], inv);
    float y2 = __fmul_rn(pr[n*4+3], inv);
    int c = threadIdx.x;
    for (int s = 0; s < 49; ++s) {
        int sy = s / 7, sx = s - sy * 7;
        float bx = __fdiv_rn(__fadd_rn((float)sx, 0.5f), 7.0f);
        float by = __fdiv_rn(__fadd_rn((float)sy, 0.5f), 7.0f);
        float xs = __fsub_rn(__fadd_rn(x1, __fmul_rn(bx, __fsub_rn(x2, x1))), 0.5f);
        float ys = __fsub_rn(__fadd_rn(y1, __fmul_rn(by, __fsub_rn(y2, y1))), 0.5f);
        float x0f = floorf(xs), y0f = floorf(ys);
        float wx = __fsub_rn(xs, x0f), wy = __fsub_rn(ys, y0f);
        int x0i = min(max((int)x0f, 0), W - 1);
        int x1i = min(x0i + 1, W - 1);
        int y0i = min(max((int)y0f, 0), W - 1);
        int y1i = min(y0i + 1, W - 1);
        const float* b00 = fT + (size_t)(y0i * W + x0i) * CCH;
        const float* b01 = fT + (size_t)(y0i * W + x1i) * CCH;
        const float* b10 = fT + (size_t)(y1i * W + x0i) * CCH;
        const float* b11 = fT + (size_t)(y1i * W + x1i) * CCH;
        float v00 = b00[c], v01 = b01[c], v10 = b10[c], v11 = b11[c];
        float omwx = __fsub_rn(1.0f, wx), omwy = __fsub_rn(1.0f, wy);
        float top = __fadd_rn(__fmul_rn(omwx, v00), __fmul_rn(wx, v01));
        float bot = __fadd_rn(__fmul_rn(omwx, v10), __fmul_rn(wx, v11));
        float val = __fadd_rn(__fmul_rn(omwy, top), __fmul_rn(wy, bot));
        A[(size_t)m * KDIM + s * CCH + c] = val;   // k' = s*256 + c
    }
}

// ---------------- fp32 GEMM: tile 128x128, BK=32, 8x8/thread, split-K ----------------
// PERM=1: B row = (k&255)*49 + (k>>8)  (w1 row permutation for A's k'=s*256+c layout)
// Writes partials Cp[z][3072][1024]; bias+relu applied in k_reduce.
template<int PERM, int SPLITK>
__global__ __launch_bounds__(256, 3) void k_gemm8(
    const float* __restrict__ A, const float* __restrict__ B,
    float* __restrict__ Cp, int K, int lda)
{
    __shared__ float As[32][132];
    __shared__ float Bs[32][132];
    const int bm = blockIdx.x * 128;
    const int bn = blockIdx.y * 128;
    const int kslice = K / SPLITK;
    const int kbeg = blockIdx.z * kslice;
    const int tid = threadIdx.x;
    const int tx = tid & 15, ty = tid >> 4;
    const int r = tid >> 3, q = tid & 7;

    float acc[8][8];
    #pragma unroll
    for (int i = 0; i < 8; ++i) {
        #pragma unroll
        for (int j = 0; j < 8; ++j) acc[i][j] = 0.f;
    }

    for (int k0 = kbeg; k0 < kbeg + kslice; k0 += 32) {
        float4 av[4], bv[4];
        #pragma unroll
        for (int i = 0; i < 4; ++i) {
            av[i] = *(const float4*)(A + (size_t)(bm + r + 32 * i) * lda + (k0 + q * 4));
        }
        int krow = k0 + r;
        int brow = PERM ? ((krow & 255) * 49 + (krow >> 8)) : krow;
        #pragma unroll
        for (int i = 0; i < 4; ++i) {
            bv[i] = *(const float4*)(B + (size_t)brow * 1024 + (bn + (q + 8 * i) * 4));
        }
        __syncthreads();   // previous iteration's LDS reads complete
        #pragma unroll
        for (int i = 0; i < 4; ++i) {
            As[q * 4 + 0][r + 32 * i] = av[i].x;
            As[q * 4 + 1][r + 32 * i] = av[i].y;
            As[q * 4 + 2][r + 32 * i] = av[i].z;
            As[q * 4 + 3][r + 32 * i] = av[i].w;
        }
        #pragma unroll
        for (int i = 0; i < 4; ++i) {
            *(float4*)&Bs[r][(q + 8 * i) * 4] = bv[i];
        }
        __syncthreads();
        #pragma unroll
        for (int kk = 0; kk < 32; ++kk) {
            float a0[4], a1[4], b0[4], b1[4];
            *(float4*)a0 = *(const float4*)&As[kk][ty * 4];
            *(float4*)a1 = *(const float4*)&As[kk][64 + ty * 4];
            *(float4*)b0 = *(const float4*)&Bs[kk][tx * 4];
            *(float4*)b1 = *(const float4*)&Bs[kk][64 + tx * 4];
            #pragma unroll
            for (int ii = 0; ii < 4; ++ii) {
                #pragma unroll
                for (int jj = 0; jj < 4; ++jj) {
                    acc[ii][jj]         = fmaf(a0[ii], b0[jj], acc[ii][jj]);
                    acc[ii][jj + 4]     = fmaf(a0[ii], b1[jj], acc[ii][jj + 4]);
                    acc[ii + 4][jj]     = fmaf(a1[ii], b0[jj], acc[ii + 4][jj]);
                    acc[ii + 4][jj + 4] = fmaf(a1[ii], b1[jj], acc[ii + 4][jj + 4]);
                }
            }
        }
    }

    float* Cb = Cp + (size_t)blockIdx.z * 3072 * 1024;
    #pragma unroll
    for (int ii = 0; ii < 8; ++ii) {
        int row = bm + (ii < 4 ? ty * 4 + ii : 64 + ty * 4 + (ii - 4));
        float o0[4], o1[4];
        #pragma unroll
        for (int jj = 0; jj < 4; ++jj) { o0[jj] = acc[ii][jj]; o1[jj] = acc[ii][jj + 4]; }
        *(float4*)(Cb + (size_t)row * 1024 + bn + tx * 4)      = *(float4*)o0;
        *(float4*)(Cb + (size_t)row * 1024 + bn + 64 + tx * 4) = *(float4*)o1;
    }
}

// ---------------- split-K reduce + bias + relu ----------------
template<int SPLITK>
__global__ __launch_bounds__(256) void k_reduce(
    const float* __restrict__ Cp, const float* __restrict__ bias, float* __restrict__ H)
{
    size_t base = ((size_t)blockIdx.x * 256 + threadIdx.x) * 4;  // over 3072*1024
    int col = (int)(base & 1023);
    float4 s = *(const float4*)(Cp + base);
    #pragma unroll
    for (int z = 1; z < SPLITK; ++z) {
        float4 p = *(const float4*)(Cp + (size_t)z * 3072 * 1024 + base);
        s.x += p.x; s.y += p.y; s.z += p.z; s.w += p.w;
    }
    float4 b = *(const float4*)(bias + col);
    float4 o;
    o.x = fmaxf(s.x + b.x, 0.f); o.y = fmaxf(s.y + b.y, 0.f);
    o.z = fmaxf(s.z + b.z, 0.f); o.w = fmaxf(s.w + b.w, 0.f);
    *(float4*)(H + base) = o;
}

// ---------------- wc (1024x20) -> wcT (20x1024) ----------------
__global__ __launch_bounds__(256) void k_wct(const float* __restrict__ wc, float* __restrict__ wcT)
{
    int t = blockIdx.x * 256 + threadIdx.x;
    if (t >= NCLS * 1024) return;
    int k = t & 1023, c = t >> 10;
    wcT[t] = wc[k * NCLS + c];
}

// ---------------- classifier head: wave-parallel dot products ----------------
__global__ __launch_bounds__(256) void k_head2(
    const float* __restrict__ h2, const float* __restrict__ wcT, const float* __restrict__ bc,
    float* __restrict__ scores, float* __restrict__ classesF)
{
    __shared__ float hrow[1024];
    __shared__ float probs[NCLS];
    int m = blockIdx.x, tid = threadIdx.x;
    *(float4*)&hrow[tid << 2] = *(const float4*)(h2 + (size_t)m * 1024 + (tid << 2));
    __syncthreads();
    int w = tid >> 6, lane = tid & 63;
    for (int cg = 0; cg < 5; ++cg) {
        int cls = w * 5 + cg;
        float acc = 0.f;
        #pragma unroll
        for (int j = 0; j < 16; ++j) {
            int k = lane + 64 * j;
            acc = fmaf(hrow[k], wcT[cls * 1024 + k], acc);
        }
        #pragma unroll
        for (int off = 32; off > 0; off >>= 1)
            acc += __shfl_down(acc, off);
        if (lane == 0) {
            float logit = __fadd_rn(acc, bc[cls]);
            probs[cls] = __fdiv_rn(1.0f, __fadd_rn(1.0f, expf(-logit)));
        }
    }
    __syncthreads();
    if (tid == 0) {
        float best = -1.0f; int bi = 0;
        for (int n2 = 0; n2 < NCLS; ++n2) {
            float p = probs[n2];
            if (p > best) { best = p; bi = n2; }
        }
        scores[m] = best;
        classesF[m] = (float)bi;
    }
}

// ---------------- global max over all box coords ----------------
__global__ __launch_bounds__(1024) void k_boxmax(const float* __restrict__ a,
                                                 const float* __restrict__ b,
                                                 const float* __restrict__ c,
                                                 float* __restrict__ maxv)
{
    __shared__ float red[1024];
    int tid = threadIdx.x;
    float v = -1e30f;
    for (int i = tid; i < 4000; i += 1024) {
        v = fmaxf(v, a[i]); v = fmaxf(v, b[i]); v = fmaxf(v, c[i]);
    }
    red[tid] = v; __syncthreads();
    for (int s = 512; s > 0; s >>= 1) {
        if (tid < s) red[tid] = fmaxf(red[tid], red[tid + s]);
        __syncthreads();
    }
    if (tid == 0) maxv[0] = red[0];
}

// ---------------- per-box class-offset box + area ----------------
__global__ __launch_bounds__(256) void k_prep(
    const float* __restrict__ pr3, const float* __restrict__ pr4, const float* __restrict__ pr5,
    const float* __restrict__ classesF, const float* __restrict__ maxv,
    float* __restrict__ obox, float* __restrict__ area)
{
    int i = blockIdx.x * 256 + threadIdx.x;
    if (i >= NBOX) return;
    int lvl = i / 1000, n = i - lvl * 1000;
    const float* pr = lvl == 0 ? pr3 : (lvl == 1 ? pr4 : pr5);
    float off = __fmul_rn(classesF[i], __fadd_rn(maxv[0], 1.0f));
    float b0 = __fadd_rn(pr[n*4+0], off);
    float b1 = __fadd_rn(pr[n*4+1], off);
    float b2 = __fadd_rn(pr[n*4+2], off);
    float b3 = __fadd_rn(pr[n*4+3], off);
    obox[i*4+0] = b0; obox[i*4+1] = b1; obox[i*4+2] = b2; obox[i*4+3] = b3;
    area[i] = __fmul_rn(fmaxf(__fsub_rn(b2, b0), 0.f), fmaxf(__fsub_rn(b3, b1), 0.f));
}

// ---------------- bitonic argsort (score desc, idx asc == stable argsort(-s)) ----------------
__global__ __launch_bounds__(1024) void k_sort(const float* __restrict__ scores,
                                               int* __restrict__ ord, float* __restrict__ ssort)
{
    __shared__ float ss[4096];
    __shared__ int   si[4096];
    int tid = threadIdx.x;
    for (int t = tid; t < 4096; t += 1024) {
        if (t < NBOX) { ss[t] = scores[t]; si[t] = t; }
        else          { ss[t] = -__builtin_inff(); si[t] = t; }
    }
    __syncthreads();
    for (int k = 2; k <= 4096; k <<= 1) {
        for (int j = k >> 1; j > 0; j >>= 1) {
            for (int t = tid; t < 4096; t += 1024) {
                int l = t ^ j;
                if (l > t) {
                    float st = ss[t], sl = ss[l];
                    int it = si[t], il = si[l];
                    bool up = ((t & k) == 0);
                    bool lLessT = (sl > st) || (sl == st && il < it);
                    if (lLessT == up) { ss[t] = sl; ss[l] = st; si[t] = il; si[l] = it; }
                }
            }
            __syncthreads();
        }
    }
    for (int t = tid; t < NBOX; t += 1024) { ord[t] = si[t]; ssort[t] = ss[t]; }
}

// ---------------- suppression bitmask ----------------
__global__ __launch_bounds__(256) void k_sup(
    const int* __restrict__ ord, const float* __restrict__ obox, const float* __restrict__ area,
    u64* __restrict__ sup)
{
    int i = blockIdx.x;
    int w = blockIdx.y * 4 + (threadIdx.x >> 6);
    int lane = threadIdx.x & 63;
    if (w >= NW) return;
    int j = (w << 6) + lane;
    bool s = false;
    int oi = ord[i];
    float bi0 = obox[oi*4+0], bi1 = obox[oi*4+1], bi2 = obox[oi*4+2], bi3 = obox[oi*4+3];
    float ai = area[oi];
    if (j > i && j < NBOX) {
        int oj = ord[j];
        float bj0 = obox[oj*4+0], bj1 = obox[oj*4+1], bj2 = obox[oj*4+2], bj3 = obox[oj*4+3];
        float lt0 = fmaxf(bi0, bj0), lt1 = fmaxf(bi1, bj1);
        float rb0 = fminf(bi2, bj2), rb1 = fminf(bi3, bj3);
        float w0 = fmaxf(__fsub_rn(rb0, lt0), 0.f), w1 = fmaxf(__fsub_rn(rb1, lt1), 0.f);
        float inter = __fmul_rn(w0, w1);
        float den = __fadd_rn(__fsub_rn(__fadd_rn(ai, area[oj]), inter), 1e-8f);
        float iou = __fdiv_rn(inter, den);
        s = iou > 0.5f;
    }
    u64 mask = __ballot(s);
    if (lane == 0) sup[(size_t)i * NW + w] = mask;
}

// ---------------- NMS scan: chunked, double-buffered LDS ----------------
__global__ __launch_bounds__(256) void k_nms2(
    const float* __restrict__ ssort, const u64* __restrict__ sup, u64* __restrict__ rem)
{
    __shared__ u64 buf[2][64 * NW];   // 2 x 24,064 B
    int tid = threadIdx.x;
    int lane = tid & 63;
    u64 r = 0;
    if (tid < NW) {
        for (int b = 0; b < 64; ++b) {
            int idx = (tid << 6) + b;
            if (idx < NBOX && ssort[idx] >= 0.05f) r |= (1ull << b);
        }
    }
    // preload chunk 0
    for (int t = tid; t < 64 * NW; t += 256) buf[0][t] = sup[t];
    __syncthreads();
    const int NCHUNK = (NBOX + 63) >> 6;   // 47
    for (int c = 0; c < NCHUNK; ++c) {
        int cur = c & 1;
        if (c + 1 < NCHUNK) {
            size_t base = (size_t)(c + 1) * 64 * NW;
            for (int t = tid; t < 64 * NW; t += 256)
                if (base + t < (size_t)NBOX * NW) buf[cur ^ 1][t] = sup[base + t];
        }
        if (tid < 64) {
            for (int b = 0; b < 64; ++b) {
                int i = (c << 6) + b;
                if (i >= NBOX) break;
                unsigned lo = __shfl((unsigned)(r & 0xffffffffull), c);
                unsigned hi = __shfl((unsigned)(r >> 32), c);
                u64 wv = ((u64)hi << 32) | lo;
                if ((wv >> b) & 1ull) {
                    if (lane < NW) r &= ~buf[cur][b * NW + lane];
                }
            }
        }
        __syncthreads();
    }
    if (tid < NW) rem[tid] = r;
}

// ---------------- final output assembly ----------------
__global__ __launch_bounds__(256) void k_out(
    const float* __restrict__ pr3, const float* __restrict__ pr4, const float* __restrict__ pr5,
    const float* __restrict__ classesF, const float* __restrict__ scores,
    const int* __restrict__ ord, const u64* __restrict__ rem, float* __restrict__ out)
{
    int t = blockIdx.x * 256 + threadIdx.x;
    if (t >= 21000) return;
    if (t < 12000) {
        int m = t >> 2, j = t & 3;
        int lvl = m / 1000, n = m - lvl * 1000;
        const float* pr = lvl == 0 ? pr3 : (lvl == 1 ? pr4 : pr5);
        out[t] = pr[n*4 + j];
    } else if (t < 15000) {
        out[t] = classesF[t - 12000];
    } else if (t < 18000) {
        out[t] = scores[t - 15000];
    } else {
        int p = t - 18000;
        int orig = ord[p];
        int bit = (int)((rem[p >> 6] >> (p & 63)) & 1ull);
        out[18000 + orig] = (float)bit;
    }
}

extern "C" void kernel_launch(void* const* d_in, const int* in_sizes, int n_in,
                              void* d_out, int out_size, void* d_ws, size_t ws_size,
                              hipStream_t stream)
{
    const float* p3  = (const float*)d_in[0];
    const float* p4  = (const float*)d_in[1];
    const float* p5  = (const float*)d_in[2];
    const float* pr3 = (const float*)d_in[3];
    const float* pr4 = (const float*)d_in[4];
    const float* pr5 = (const float*)d_in[5];
    const float* w1  = (const float*)d_in[6];
    const float* b1  = (const float*)d_in[7];
    const float* w2  = (const float*)d_in[8];
    const float* b2  = (const float*)d_in[9];
    const float* wc  = (const float*)d_in[10];
    const float* bc  = (const float*)d_in[11];

    float* ws    = (float*)d_ws;
    float* fT3   = ws + OFF_FT3;
    float* fT4   = ws + OFF_FT4;
    float* fT5   = ws + OFF_FT5;
    float* A     = ws + OFF_A;
    float* h1    = ws + OFF_H1;
    float* h2    = ws + OFF_H2;
    float* sc    = ws + OFF_SC;
    float* clf   = ws + OFF_CL;
    float* maxv  = ws + OFF_MAXV;
    float* obox  = ws + OFF_OBOX;
    float* area  = ws + OFF_AREA;
    int*   ord   = (int*)(ws + OFF_ORD);
    float* ssort = ws + OFF_SSORT;
    u64*   sup   = (u64*)(ws + OFF_SUP);
    u64*   rem   = (u64*)(ws + OFF_REM);
    float* Cp    = ws + OFF_CP;
    float* wcT   = ws + OFF_WCT;
    float* out   = (float*)d_out;

    k_transpose2<<<dim3(256, 4), 256, 0, stream>>>(p3, fT3, 128 * 128);
    k_transpose2<<<dim3(64, 4),  256, 0, stream>>>(p4, fT4, 64 * 64);
    k_transpose2<<<dim3(16, 4),  256, 0, stream>>>(p5, fT5, 32 * 32);
    k_roialign2<<<NBOX, 256, 0, stream>>>(fT3, fT4, fT5, pr3, pr4, pr5, A);
    k_boxmax<<<1, 1024, 0, stream>>>(pr3, pr4, pr5, maxv);
    k_wct<<<(NCLS * 1024 + 255) / 256, 256, 0, stream>>>(wc, wcT);

    k_gemm8<1, 4><<<dim3(24, 8, 4), 256, 0, stream>>>(A, w1, Cp, KDIM, KDIM);
    k_reduce<4><<<3072, 256, 0, stream>>>(Cp, b1, h1);
    k_gemm8<0, 4><<<dim3(24, 8, 4), 256, 0, stream>>>(h1, w2, Cp, 1024, 1024);
    k_reduce<4><<<3072, 256, 0, stream>>>(Cp, b2, h2);

    k_head2<<<NBOX, 256, 0, stream>>>(h2, wcT, bc, sc, clf);
    k_prep<<<12, 256, 0, stream>>>(pr3, pr4, pr5, clf, maxv, obox, area);
    k_sort<<<1, 1024, 0, stream>>>(sc, ord, ssort);
    k_sup<<<dim3(NBOX, 12), 256, 0, stream>>>(ord, obox, area, sup);
    k_nms2<<<1, 256, 0, stream>>>(ssort, sup, rem);
    k_out<<<(21000 + 255) / 256, 256, 0, stream>>>(pr3, pr4, pr5, clf, sc, ord, rem, out);
}

// Round 6
// 1430.015 us; speedup vs baseline: 1.7474x; 1.3425x over previous
//
#include <hip/hip_runtime.h>
#include <cstdint>

typedef unsigned long long u64;
typedef _Float16 f16;
typedef _Float16 f16x4 __attribute__((ext_vector_type(4)));
typedef _Float16 f16x8 __attribute__((ext_vector_type(8)));
typedef float f32x4 __attribute__((ext_vector_type(4)));

#define NBOX 3000
#define CCH  256
#define KDIM 12544   // 256*49
#define NCLS 20
#define NW   47      // ceil(3000/64) u64 words
#define L2SCALE 2048.0f          // 2^11
#define L2INV   4.8828125e-4f    // 2^-11
#define LDSPAD 40                // f16 row stride in LDS (80B -> conflict-free frag reads)

// ---------------- workspace layout (float offsets), aliased by liveness ----------------
// Cp [3 x 3072 x 1024 f32] : written by GEMMs.  FT3/4/5 (dead after roialign) alias inside.
static constexpr size_t OFF_CP   = 0;            // 9,437,184 floats
static constexpr size_t OFF_FT3  = 0;            //   4,194,304 (alias in Cp)
static constexpr size_t OFF_FT4  = 4194304;      //   1,048,576
static constexpr size_t OFF_FT5  = 5242880;      //     262,144 (ends 5,505,024 < 9,437,184)
static constexpr size_t OFF_AH   = 9437184;      // 3072x12544 f16 = 19,267,584 floats
static constexpr size_t OFF_AL   = 28704768;     // ends 47,972,352
static constexpr size_t OFF_B1HT = 47972352;     // 1024x12544 f16 = 6,422,528 floats
static constexpr size_t OFF_B1LT = 54394880;     // ends 60,817,408
// --- aliases valid only AFTER GEMM1 (B1 dead): ---
static constexpr size_t OFF_H1H  = 47972352;     // 3072x1024 f16 = 1,572,864 floats
static constexpr size_t OFF_H1L  = 49545216;
static constexpr size_t OFF_H2   = 51118080;     // 3072x1024 f32 (ends 54,263,808)
static constexpr size_t OFF_SC   = 54394880;
static constexpr size_t OFF_CL   = 54397952;
static constexpr size_t OFF_MAXV = 54401024;
static constexpr size_t OFF_OBOX = 54401088;
static constexpr size_t OFF_AREA = 54413120;
static constexpr size_t OFF_ORD  = 54416128;     // int
static constexpr size_t OFF_SSORT= 54419200;
static constexpr size_t OFF_SUP  = 54422272;     // u64[3000*47] (byte off %8==0)
static constexpr size_t OFF_REM  = 54704272;     // u64[47]
static constexpr size_t OFF_WCT  = 54704384;     // 20x1024 f32 (ends 54,724,864 < 60,817,408)
// --- end aliases ---
static constexpr size_t OFF_B2HT = 60817408;     // 1024x1024 f16 = 524,288 floats
static constexpr size_t OFF_B2LT = 61341696;     // ends 61,865,984
// total = 61,865,984 floats = 247.46 MB  (round-1's 253 MB passed -> safe)

// ---------------- CHW -> HWC transpose, LDS-tiled 64x64 ----------------
__global__ __launch_bounds__(256) void k_transpose2(const float* __restrict__ in,
                                                    float* __restrict__ out, int HW)
{
    __shared__ float t[64][65];
    int pb = blockIdx.x * 64;
    int cb = blockIdx.y * 64;
    int tid = threadIdx.x;
    int x = tid & 63, y4 = tid >> 6;
    #pragma unroll
    for (int i = 0; i < 16; ++i) {
        int cr = y4 + i * 4;
        t[x][cr] = in[(size_t)(cb + cr) * HW + pb + x];
    }
    __syncthreads();
    #pragma unroll
    for (int i = 0; i < 16; ++i) {
        int pr = y4 + i * 4;
        out[(size_t)(pb + pr) * CCH + cb + x] = t[pr][x];
    }
}

// ---------------- ROI align: one block per box; writes fp16 h/l splits ----------------
__global__ __launch_bounds__(256) void k_roialign2(
    const float* __restrict__ fT3, const float* __restrict__ fT4, const float* __restrict__ fT5,
    const float* __restrict__ pr3, const float* __restrict__ pr4, const float* __restrict__ pr5,
    f16* __restrict__ Ah, f16* __restrict__ Al)
{
    int m = blockIdx.x;
    int lvl = m / 1000, n = m - lvl * 1000;
    const float* pr; const float* fT; int W; float inv;
    if (lvl == 0)      { pr = pr3; fT = fT3; W = 128; inv = 0.125f;   }
    else if (lvl == 1) { pr = pr4; fT = fT4; W = 64;  inv = 0.0625f;  }
    else               { pr = pr5; fT = fT5; W = 32;  inv = 0.03125f; }

    float x1 = __fmul_rn(pr[n*4+0], inv);
    float y1 = __fmul_rn(pr[n*4+1], inv);
    float x2 = __fmul_rn(pr[n*4+2], inv);
    float y2 = __fmul_rn(pr[n*4+3], inv);
    int c = threadIdx.x;
    for (int s = 0; s < 49; ++s) {
        int sy = s / 7, sx = s - sy * 7;
        float bx = __fdiv_rn(__fadd_rn((float)sx, 0.5f), 7.0f);
        float by = __fdiv_rn(__fadd_rn((float)sy, 0.5f), 7.0f);
        float xs = __fsub_rn(__fadd_rn(x1, __fmul_rn(bx, __fsub_rn(x2, x1))), 0.5f);
        float ys = __fsub_rn(__fadd_rn(y1, __fmul_rn(by, __fsub_rn(y2, y1))), 0.5f);
        float x0f = floorf(xs), y0f = floorf(ys);
        float wx = __fsub_rn(xs, x0f), wy = __fsub_rn(ys, y0f);
        int x0i = min(max((int)x0f, 0), W - 1);
        int x1i = min(x0i + 1, W - 1);
        int y0i = min(max((int)y0f, 0), W - 1);
        int y1i = min(y0i + 1, W - 1);
        const float* b00 = fT + (size_t)(y0i * W + x0i) * CCH;
        const float* b01 = fT + (size_t)(y0i * W + x1i) * CCH;
        const float* b10 = fT + (size_t)(y1i * W + x0i) * CCH;
        const float* b11 = fT + (size_t)(y1i * W + x1i) * CCH;
        float v00 = b00[c], v01 = b01[c], v10 = b10[c], v11 = b11[c];
        float omwx = __fsub_rn(1.0f, wx), omwy = __fsub_rn(1.0f, wy);
        float top = __fadd_rn(__fmul_rn(omwx, v00), __fmul_rn(wx, v01));
        float bot = __fadd_rn(__fmul_rn(omwx, v10), __fmul_rn(wx, v11));
        float val = __fadd_rn(__fmul_rn(omwy, top), __fmul_rn(wy, bot));
        f16 h = (f16)val;
        f16 l = (f16)(__fsub_rn(val, (float)h) * L2SCALE);
        size_t idx = (size_t)m * KDIM + s * CCH + c;   // k' = s*256 + c
        Ah[idx] = h;
        Al[idx] = l;
    }
}

// ---------------- B transpose + fp16 split (perm baked for w1) ----------------
template<int PERM>
__global__ __launch_bounds__(256) void k_splitT(const float* __restrict__ Bin,
                                                f16* __restrict__ BhT, f16* __restrict__ BlT,
                                                int K)
{
    __shared__ float t[64][65];
    int kb = blockIdx.x * 64;
    int nb = blockIdx.y * 64;
    int tid = threadIdx.x;
    int x = tid & 63, y4 = tid >> 6;
    #pragma unroll
    for (int i = 0; i < 16; ++i) {
        int r = y4 + i * 4;           // local k index
        int kk = kb + r;
        int row = PERM ? ((kk & 255) * 49 + (kk >> 8)) : kk;
        t[r][x] = Bin[(size_t)row * 1024 + nb + x];
    }
    __syncthreads();
    #pragma unroll
    for (int i = 0; i < 16; ++i) {
        int r = y4 + i * 4;           // local n index
        float v = t[x][r];
        f16 h = (f16)v;
        f16 l = (f16)(__fsub_rn(v, (float)h) * L2SCALE);
        size_t o = (size_t)(nb + r) * K + kb + x;
        BhT[o] = h;
        BlT[o] = l;
    }
}

// ---------------- MFMA emulated-fp32 GEMM, tile 128x128, K-step 32, ragged split-K ----------------
// C = Ah*Bh + 2^-11 (Ah*Bl' + Al'*Bh)
template<int SPLITK>
__global__ __launch_bounds__(256) void k_gemm_mfma(
    const f16* __restrict__ Ah, const f16* __restrict__ Al,
    const f16* __restrict__ BhT, const f16* __restrict__ BlT,
    float* __restrict__ Cp, int K)
{
    __shared__ f16 sAh[128 * LDSPAD];
    __shared__ f16 sAl[128 * LDSPAD];
    __shared__ f16 sBh[128 * LDSPAD];
    __shared__ f16 sBl[128 * LDSPAD];
    const int bm = blockIdx.x * 128;
    const int bn = blockIdx.y * 128;
    // ragged K split over 32-wide steps
    const int S = K >> 5;
    const int base = S / SPLITK, rem = S - base * SPLITK;
    const int z = blockIdx.z;
    const int s0 = z * base + min(z, rem);
    const int ns = base + (z < rem ? 1 : 0);
    const int kbeg = s0 << 5;
    const int tid = threadIdx.x;
    const int lane = tid & 63;
    const int wid = tid >> 6;           // 4 waves: 2x2
    const int wr = wid >> 1, wc = wid & 1;
    const int lr = lane & 15;
    const int kg = lane >> 4;           // 0..3

    f32x4 acc1[4][4], acc2[4][4];
    #pragma unroll
    for (int i = 0; i < 4; ++i) {
        #pragma unroll
        for (int j = 0; j < 4; ++j) {
            acc1[i][j] = (f32x4)0.f;
            acc2[i][j] = (f32x4)0.f;
        }
    }

    // staging: tile = 128 rows x 32 f16 = 512 x 16B chunks; thread does chunks tid, tid+256
    const int c0 = tid, c1 = tid + 256;
    const int r0 = c0 >> 2, o0 = (c0 & 3) * 8;
    const int r1 = c1 >> 2, o1 = (c1 & 3) * 8;

    for (int ks = 0; ks < ns; ++ks) {
        const int k0 = kbeg + (ks << 5);
        float4 va0 = *(const float4*)(Ah  + (size_t)(bm + r0) * K + k0 + o0);
        float4 va1 = *(const float4*)(Ah  + (size_t)(bm + r1) * K + k0 + o1);
        float4 vb0 = *(const float4*)(Al  + (size_t)(bm + r0) * K + k0 + o0);
        float4 vb1 = *(const float4*)(Al  + (size_t)(bm + r1) * K + k0 + o1);
        float4 vc0 = *(const float4*)(BhT + (size_t)(bn + r0) * K + k0 + o0);
        float4 vc1 = *(const float4*)(BhT + (size_t)(bn + r1) * K + k0 + o1);
        float4 vd0 = *(const float4*)(BlT + (size_t)(bn + r0) * K + k0 + o0);
        float4 vd1 = *(const float4*)(BlT + (size_t)(bn + r1) * K + k0 + o1);
        __syncthreads();   // previous iteration's fragment reads complete
        *(float4*)&sAh[r0 * LDSPAD + o0] = va0;
        *(float4*)&sAh[r1 * LDSPAD + o1] = va1;
        *(float4*)&sAl[r0 * LDSPAD + o0] = vb0;
        *(float4*)&sAl[r1 * LDSPAD + o1] = vb1;
        *(float4*)&sBh[r0 * LDSPAD + o0] = vc0;
        *(float4*)&sBh[r1 * LDSPAD + o1] = vc1;
        *(float4*)&sBl[r0 * LDSPAD + o0] = vd0;
        *(float4*)&sBl[r1 * LDSPAD + o1] = vd1;
        __syncthreads();

        f16x8 bh[4], bl[4];
        #pragma unroll
        for (int fj = 0; fj < 4; ++fj) {
            bh[fj] = *(const f16x8*)&sBh[(wc * 64 + fj * 16 + lr) * LDSPAD + kg * 8];
            bl[fj] = *(const f16x8*)&sBl[(wc * 64 + fj * 16 + lr) * LDSPAD + kg * 8];
        }
        #pragma unroll
        for (int fi = 0; fi < 4; ++fi) {
            f16x8 ah = *(const f16x8*)&sAh[(wr * 64 + fi * 16 + lr) * LDSPAD + kg * 8];
            f16x8 al = *(const f16x8*)&sAl[(wr * 64 + fi * 16 + lr) * LDSPAD + kg * 8];
            #pragma unroll
            for (int fj = 0; fj < 4; ++fj) {
                acc2[fi][fj] = __builtin_amdgcn_mfma_f32_16x16x32_f16(al, bh[fj], acc2[fi][fj], 0, 0, 0);
                acc2[fi][fj] = __builtin_amdgcn_mfma_f32_16x16x32_f16(ah, bl[fj], acc2[fi][fj], 0, 0, 0);
                acc1[fi][fj] = __builtin_amdgcn_mfma_f32_16x16x32_f16(ah, bh[fj], acc1[fi][fj], 0, 0, 0);
            }
        }
    }

    float* Cb = Cp + (size_t)z * 3072 * 1024;
    #pragma unroll
    for (int fi = 0; fi < 4; ++fi) {
        #pragma unroll
        for (int fj = 0; fj < 4; ++fj) {
            #pragma unroll
            for (int r = 0; r < 4; ++r) {
                int row = bm + wr * 64 + fi * 16 + kg * 4 + r;
                int col = bn + wc * 64 + fj * 16 + lr;
                Cb[(size_t)row * 1024 + col] = acc1[fi][fj][r] + L2INV * acc2[fi][fj][r];
            }
        }
    }
}

// ---------------- split-K reduce + bias + relu -> fp16 h/l splits (FC1) ----------------
template<int SPLITK>
__global__ __launch_bounds__(256) void k_reduce_split(
    const float* __restrict__ Cp, const float* __restrict__ bias,
    f16* __restrict__ Hh, f16* __restrict__ Hl)
{
    size_t base = ((size_t)blockIdx.x * 256 + threadIdx.x) * 4;
    int col = (int)(base & 1023);
    float4 s = *(const float4*)(Cp + base);
    #pragma unroll
    for (int zz = 1; zz < SPLITK; ++zz) {
        float4 p = *(const float4*)(Cp + (size_t)zz * 3072 * 1024 + base);
        s.x += p.x; s.y += p.y; s.z += p.z; s.w += p.w;
    }
    float4 b = *(const float4*)(bias + col);
    float o[4];
    o[0] = fmaxf(s.x + b.x, 0.f); o[1] = fmaxf(s.y + b.y, 0.f);
    o[2] = fmaxf(s.z + b.z, 0.f); o[3] = fmaxf(s.w + b.w, 0.f);
    f16x4 hv, lv;
    #pragma unroll
    for (int j = 0; j < 4; ++j) {
        f16 h = (f16)o[j];
        hv[j] = h;
        lv[j] = (f16)(__fsub_rn(o[j], (float)h) * L2SCALE);
    }
    *(f16x4*)(Hh + base) = hv;
    *(f16x4*)(Hl + base) = lv;
}

// ---------------- split-K reduce + bias + relu -> fp32 (FC2) ----------------
template<int SPLITK>
__global__ __launch_bounds__(256) void k_reduce_f32(
    const float* __restrict__ Cp, const float* __restrict__ bias, float* __restrict__ H)
{
    size_t base = ((size_t)blockIdx.x * 256 + threadIdx.x) * 4;
    int col = (int)(base & 1023);
    float4 s = *(const float4*)(Cp + base);
    #pragma unroll
    for (int zz = 1; zz < SPLITK; ++zz) {
        float4 p = *(const float4*)(Cp + (size_t)zz * 3072 * 1024 + base);
        s.x += p.x; s.y += p.y; s.z += p.z; s.w += p.w;
    }
    float4 b = *(const float4*)(bias + col);
    float4 o;
    o.x = fmaxf(s.x + b.x, 0.f); o.y = fmaxf(s.y + b.y, 0.f);
    o.z = fmaxf(s.z + b.z, 0.f); o.w = fmaxf(s.w + b.w, 0.f);
    *(float4*)(H + base) = o;
}

// ---------------- wc (1024x20) -> wcT (20x1024) ----------------
__global__ __launch_bounds__(256) void k_wct(const float* __restrict__ wc, float* __restrict__ wcT)
{
    int t = blockIdx.x * 256 + threadIdx.x;
    if (t >= NCLS * 1024) return;
    int k = t & 1023, c = t >> 10;
    wcT[t] = wc[k * NCLS + c];
}

// ---------------- classifier head: wave-parallel dot products (fp32) ----------------
__global__ __launch_bounds__(256) void k_head2(
    const float* __restrict__ h2, const float* __restrict__ wcT, const float* __restrict__ bc,
    float* __restrict__ scores, float* __restrict__ classesF)
{
    __shared__ float hrow[1024];
    __shared__ float probs[NCLS];
    int m = blockIdx.x, tid = threadIdx.x;
    *(float4*)&hrow[tid << 2] = *(const float4*)(h2 + (size_t)m * 1024 + (tid << 2));
    __syncthreads();
    int w = tid >> 6, lane = tid & 63;
    for (int cg = 0; cg < 5; ++cg) {
        int cls = w * 5 + cg;
        float acc = 0.f;
        #pragma unroll
        for (int j = 0; j < 16; ++j) {
            int k = lane + 64 * j;
            acc = fmaf(hrow[k], wcT[cls * 1024 + k], acc);
        }
        #pragma unroll
        for (int off = 32; off > 0; off >>= 1)
            acc += __shfl_down(acc, off);
        if (lane == 0) {
            float logit = __fadd_rn(acc, bc[cls]);
            probs[cls] = __fdiv_rn(1.0f, __fadd_rn(1.0f, expf(-logit)));
        }
    }
    __syncthreads();
    if (tid == 0) {
        float best = -1.0f; int bi = 0;
        for (int n2 = 0; n2 < NCLS; ++n2) {
            float p = probs[n2];
            if (p > best) { best = p; bi = n2; }
        }
        scores[m] = best;
        classesF[m] = (float)bi;
    }
}

// ---------------- global max over all box coords ----------------
__global__ __launch_bounds__(1024) void k_boxmax(const float* __restrict__ a,
                                                 const float* __restrict__ b,
                                                 const float* __restrict__ c,
                                                 float* __restrict__ maxv)
{
    __shared__ float red[1024];
    int tid = threadIdx.x;
    float v = -1e30f;
    for (int i = tid; i < 4000; i += 1024) {
        v = fmaxf(v, a[i]); v = fmaxf(v, b[i]); v = fmaxf(v, c[i]);
    }
    red[tid] = v; __syncthreads();
    for (int s = 512; s > 0; s >>= 1) {
        if (tid < s) red[tid] = fmaxf(red[tid], red[tid + s]);
        __syncthreads();
    }
    if (tid == 0) maxv[0] = red[0];
}

// ---------------- per-box class-offset box + area ----------------
__global__ __launch_bounds__(256) void k_prep(
    const float* __restrict__ pr3, const float* __restrict__ pr4, const float* __restrict__ pr5,
    const float* __restrict__ classesF, const float* __restrict__ maxv,
    float* __restrict__ obox, float* __restrict__ area)
{
    int i = blockIdx.x * 256 + threadIdx.x;
    if (i >= NBOX) return;
    int lvl = i / 1000, n = i - lvl * 1000;
    const float* pr = lvl == 0 ? pr3 : (lvl == 1 ? pr4 : pr5);
    float off = __fmul_rn(classesF[i], __fadd_rn(maxv[0], 1.0f));
    float b0 = __fadd_rn(pr[n*4+0], off);
    float b1 = __fadd_rn(pr[n*4+1], off);
    float b2 = __fadd_rn(pr[n*4+2], off);
    float b3 = __fadd_rn(pr[n*4+3], off);
    obox[i*4+0] = b0; obox[i*4+1] = b1; obox[i*4+2] = b2; obox[i*4+3] = b3;
    area[i] = __fmul_rn(fmaxf(__fsub_rn(b2, b0), 0.f), fmaxf(__fsub_rn(b3, b1), 0.f));
}

// ---------------- bitonic argsort (score desc, idx asc == stable argsort(-s)) ----------------
__global__ __launch_bounds__(1024) void k_sort(const float* __restrict__ scores,
                                               int* __restrict__ ord, float* __restrict__ ssort)
{
    __shared__ float ss[4096];
    __shared__ int   si[4096];
    int tid = threadIdx.x;
    for (int t = tid; t < 4096; t += 1024) {
        if (t < NBOX) { ss[t] = scores[t]; si[t] = t; }
        else          { ss[t] = -__builtin_inff(); si[t] = t; }
    }
    __syncthreads();
    for (int k = 2; k <= 4096; k <<= 1) {
        for (int j = k >> 1; j > 0; j >>= 1) {
            for (int t = tid; t < 4096; t += 1024) {
                int l = t ^ j;
                if (l > t) {
                    float st = ss[t], sl = ss[l];
                    int it = si[t], il = si[l];
                    bool up = ((t & k) == 0);
                    bool lLessT = (sl > st) || (sl == st && il < it);
                    if (lLessT == up) { ss[t] = sl; ss[l] = st; si[t] = il; si[l] = it; }
                }
            }
            __syncthreads();
        }
    }
    for (int t = tid; t < NBOX; t += 1024) { ord[t] = si[t]; ssort[t] = ss[t]; }
}

// ---------------- suppression bitmask ----------------
__global__ __launch_bounds__(256) void k_sup(
    const int* __restrict__ ord, const float* __restrict__ obox, const float* __restrict__ area,
    u64* __restrict__ sup)
{
    int i = blockIdx.x;
    int w = blockIdx.y * 4 + (threadIdx.x >> 6);
    int lane = threadIdx.x & 63;
    if (w >= NW) return;
    int j = (w << 6) + lane;
    bool s = false;
    int oi = ord[i];
    float bi0 = obox[oi*4+0], bi1 = obox[oi*4+1], bi2 = obox[oi*4+2], bi3 = obox[oi*4+3];
    float ai = area[oi];
    if (j > i && j < NBOX) {
        int oj = ord[j];
        float bj0 = obox[oj*4+0], bj1 = obox[oj*4+1], bj2 = obox[oj*4+2], bj3 = obox[oj*4+3];
        float lt0 = fmaxf(bi0, bj0), lt1 = fmaxf(bi1, bj1);
        float rb0 = fminf(bi2, bj2), rb1 = fminf(bi3, bj3);
        float w0 = fmaxf(__fsub_rn(rb0, lt0), 0.f), w1 = fmaxf(__fsub_rn(rb1, lt1), 0.f);
        float inter = __fmul_rn(w0, w1);
        float den = __fadd_rn(__fsub_rn(__fadd_rn(ai, area[oj]), inter), 1e-8f);
        float iou = __fdiv_rn(inter, den);
        s = iou > 0.5f;
    }
    u64 mask = __ballot(s);
    if (lane == 0) sup[(size_t)i * NW + w] = mask;
}

// ---------------- NMS scan: chunked, double-buffered LDS ----------------
__global__ __launch_bounds__(256) void k_nms2(
    const float* __restrict__ ssort, const u64* __restrict__ sup, u64* __restrict__ rem)
{
    __shared__ u64 buf[2][64 * NW];
    int tid = threadIdx.x;
    int lane = tid & 63;
    u64 r = 0;
    if (tid < NW) {
        for (int b = 0; b < 64; ++b) {
            int idx = (tid << 6) + b;
            if (idx < NBOX && ssort[idx] >= 0.05f) r |= (1ull << b);
        }
    }
    for (int t = tid; t < 64 * NW; t += 256) buf[0][t] = sup[t];
    __syncthreads();
    const int NCHUNK = (NBOX + 63) >> 6;   // 47
    for (int c = 0; c < NCHUNK; ++c) {
        int cur = c & 1;
        if (c + 1 < NCHUNK) {
            size_t base = (size_t)(c + 1) * 64 * NW;
            for (int t = tid; t < 64 * NW; t += 256)
                if (base + t < (size_t)NBOX * NW) buf[cur ^ 1][t] = sup[base + t];
        }
        if (tid < 64) {
            for (int b = 0; b < 64; ++b) {
                int i = (c << 6) + b;
                if (i >= NBOX) break;
                unsigned lo = __shfl((unsigned)(r & 0xffffffffull), c);
                unsigned hi = __shfl((unsigned)(r >> 32), c);
                u64 wv = ((u64)hi << 32) | lo;
                if ((wv >> b) & 1ull) {
                    if (lane < NW) r &= ~buf[cur][b * NW + lane];
                }
            }
        }
        __syncthreads();
    }
    if (tid < NW) rem[tid] = r;
}

// ---------------- final output assembly ----------------
__global__ __launch_bounds__(256) void k_out(
    const float* __restrict__ pr3, const float* __restrict__ pr4, const float* __restrict__ pr5,
    const float* __restrict__ classesF, const float* __restrict__ scores,
    const int* __restrict__ ord, const u64* __restrict__ rem, float* __restrict__ out)
{
    int t = blockIdx.x * 256 + threadIdx.x;
    if (t >= 21000) return;
    if (t < 12000) {
        int m = t >> 2, j = t & 3;
        int lvl = m / 1000, n = m - lvl * 1000;
        const float* pr = lvl == 0 ? pr3 : (lvl == 1 ? pr4 : pr5);
        out[t] = pr[n*4 + j];
    } else if (t < 15000) {
        out[t] = classesF[t - 12000];
    } else if (t < 18000) {
        out[t] = scores[t - 15000];
    } else {
        int p = t - 18000;
        int orig = ord[p];
        int bit = (int)((rem[p >> 6] >> (p & 63)) & 1ull);
        out[18000 + orig] = (float)bit;
    }
}

extern "C" void kernel_launch(void* const* d_in, const int* in_sizes, int n_in,
                              void* d_out, int out_size, void* d_ws, size_t ws_size,
                              hipStream_t stream)
{
    const float* p3  = (const float*)d_in[0];
    const float* p4  = (const float*)d_in[1];
    const float* p5  = (const float*)d_in[2];
    const float* pr3 = (const float*)d_in[3];
    const float* pr4 = (const float*)d_in[4];
    const float* pr5 = (const float*)d_in[5];
    const float* w1  = (const float*)d_in[6];
    const float* b1  = (const float*)d_in[7];
    const float* w2  = (const float*)d_in[8];
    const float* b2  = (const float*)d_in[9];
    const float* wc  = (const float*)d_in[10];
    const float* bc  = (const float*)d_in[11];

    float* ws    = (float*)d_ws;
    float* Cp    = ws + OFF_CP;
    float* fT3   = ws + OFF_FT3;
    float* fT4   = ws + OFF_FT4;
    float* fT5   = ws + OFF_FT5;
    f16*   Ah    = (f16*)(ws + OFF_AH);
    f16*   Al    = (f16*)(ws + OFF_AL);
    f16*   B1hT  = (f16*)(ws + OFF_B1HT);
    f16*   B1lT  = (f16*)(ws + OFF_B1LT);
    f16*   B2hT  = (f16*)(ws + OFF_B2HT);
    f16*   B2lT  = (f16*)(ws + OFF_B2LT);
    f16*   H1h   = (f16*)(ws + OFF_H1H);
    f16*   H1l   = (f16*)(ws + OFF_H1L);
    float* h2    = ws + OFF_H2;
    float* sc    = ws + OFF_SC;
    float* clf   = ws + OFF_CL;
    float* maxv  = ws + OFF_MAXV;
    float* obox  = ws + OFF_OBOX;
    float* area  = ws + OFF_AREA;
    int*   ord   = (int*)(ws + OFF_ORD);
    float* ssort = ws + OFF_SSORT;
    u64*   sup   = (u64*)(ws + OFF_SUP);
    u64*   rem   = (u64*)(ws + OFF_REM);
    float* wcT   = ws + OFF_WCT;
    float* out   = (float*)d_out;

    // ---- phase 1: prep (FT lives inside Cp space; dead before GEMM writes Cp) ----
    k_transpose2<<<dim3(256, 4), 256, 0, stream>>>(p3, fT3, 128 * 128);
    k_transpose2<<<dim3(64, 4),  256, 0, stream>>>(p4, fT4, 64 * 64);
    k_transpose2<<<dim3(16, 4),  256, 0, stream>>>(p5, fT5, 32 * 32);
    k_roialign2<<<NBOX, 256, 0, stream>>>(fT3, fT4, fT5, pr3, pr4, pr5, Ah, Al);
    k_splitT<1><<<dim3(KDIM / 64, 16), 256, 0, stream>>>(w1, B1hT, B1lT, KDIM);
    k_splitT<0><<<dim3(16, 16), 256, 0, stream>>>(w2, B2hT, B2lT, 1024);

    // ---- phase 2: GEMMs (H1/H2 alias dead B1 region) ----
    k_gemm_mfma<3><<<dim3(24, 8, 3), 256, 0, stream>>>(Ah, Al, B1hT, B1lT, Cp, KDIM);
    k_reduce_split<3><<<3072, 256, 0, stream>>>(Cp, b1, H1h, H1l);
    k_gemm_mfma<3><<<dim3(24, 8, 3), 256, 0, stream>>>(H1h, H1l, B2hT, B2lT, Cp, 1024);
    k_reduce_f32<3><<<3072, 256, 0, stream>>>(Cp, b2, h2);

    // ---- phase 3: head + NMS (smalls alias dead B1lT region -> must run after GEMM1) ----
    k_wct<<<(NCLS * 1024 + 255) / 256, 256, 0, stream>>>(wc, wcT);
    k_boxmax<<<1, 1024, 0, stream>>>(pr3, pr4, pr5, maxv);
    k_head2<<<NBOX, 256, 0, stream>>>(h2, wcT, bc, sc, clf);
    k_prep<<<12, 256, 0, stream>>>(pr3, pr4, pr5, clf, maxv, obox, area);
    k_sort<<<1, 1024, 0, stream>>>(sc, ord, ssort);
    k_sup<<<dim3(NBOX, 12), 256, 0, stream>>>(ord, obox, area, sup);
    k_nms2<<<1, 256, 0, stream>>>(ssort, sup, rem);
    k_out<<<(21000 + 255) / 256, 256, 0, stream>>>(pr3, pr4, pr5, clf, sc, ord, rem, out);
}

// Round 7
// 1167.235 us; speedup vs baseline: 2.1408x; 1.2251x over previous
//
#include <hip/hip_runtime.h>
#include <cstdint>

typedef unsigned long long u64;
typedef _Float16 f16;
typedef _Float16 f16x4 __attribute__((ext_vector_type(4)));
typedef _Float16 f16x8 __attribute__((ext_vector_type(8)));
typedef float f32x4 __attribute__((ext_vector_type(4)));

#define NBOX 3000
#define CCH  256
#define KDIM 12544   // 256*49
#define NCLS 20
#define NW   47      // ceil(3000/64) u64 words
#define L2SCALE 2048.0f          // 2^11
#define L2INV   4.8828125e-4f    // 2^-11
#define LDSPAD 40                // f16 row stride in LDS (80B -> conflict-light frag reads)

// ---------------- workspace layout (float offsets), aliased by liveness ----------------
static constexpr size_t OFF_CP   = 0;            // 3 x 3072 x 1024 f32 = 9,437,184 floats
static constexpr size_t OFF_FT3  = 0;            //   alias in Cp (dead before GEMM)
static constexpr size_t OFF_FT4  = 4194304;
static constexpr size_t OFF_FT5  = 5242880;      //   ends 5,505,024 < 9,437,184
static constexpr size_t OFF_AH   = 9437184;      // 3072x12544 f16
static constexpr size_t OFF_AL   = 28704768;     // ends 47,972,352
static constexpr size_t OFF_B1HT = 47972352;     // 1024x12544 f16
static constexpr size_t OFF_B1LT = 54394880;     // ends 60,817,408
// --- aliases valid only AFTER GEMM1 (B1 dead): ---
static constexpr size_t OFF_H1H  = 47972352;
static constexpr size_t OFF_H1L  = 49545216;
static constexpr size_t OFF_H2   = 51118080;     // ends 54,263,808
static constexpr size_t OFF_SC   = 54394880;
static constexpr size_t OFF_CL   = 54397952;
static constexpr size_t OFF_MAXV = 54401024;
static constexpr size_t OFF_OBOX = 54401088;
static constexpr size_t OFF_AREA = 54413120;
static constexpr size_t OFF_ORD  = 54416128;     // int
static constexpr size_t OFF_SSORT= 54419200;
static constexpr size_t OFF_SUP  = 54422272;     // u64[3000*47]
static constexpr size_t OFF_REM  = 54704272;     // u64[47]
static constexpr size_t OFF_WCT  = 54704384;     // ends 54,724,864
// --- end aliases ---
static constexpr size_t OFF_B2HT = 60817408;
static constexpr size_t OFF_B2LT = 61341696;     // ends 61,865,984
// total = 61,865,984 floats = 247.46 MB

// ---------------- CHW -> HWC transpose, LDS-tiled 64x64 ----------------
__global__ __launch_bounds__(256) void k_transpose2(const float* __restrict__ in,
                                                    float* __restrict__ out, int HW)
{
    __shared__ float t[64][65];
    int pb = blockIdx.x * 64;
    int cb = blockIdx.y * 64;
    int tid = threadIdx.x;
    int x = tid & 63, y4 = tid >> 6;
    #pragma unroll
    for (int i = 0; i < 16; ++i) {
        int cr = y4 + i * 4;
        t[x][cr] = in[(size_t)(cb + cr) * HW + pb + x];
    }
    __syncthreads();
    #pragma unroll
    for (int i = 0; i < 16; ++i) {
        int pr = y4 + i * 4;
        out[(size_t)(pb + pr) * CCH + cb + x] = t[pr][x];
    }
}

// ---------------- ROI align: block = (box, 7-sample group); writes fp16 h/l splits ----------------
__global__ __launch_bounds__(256) void k_roialign2(
    const float* __restrict__ fT3, const float* __restrict__ fT4, const float* __restrict__ fT5,
    const float* __restrict__ pr3, const float* __restrict__ pr4, const float* __restrict__ pr5,
    f16* __restrict__ Ah, f16* __restrict__ Al)
{
    int m = blockIdx.x;
    int lvl = m / 1000, n = m - lvl * 1000;
    const float* pr; const float* fT; int W; float inv;
    if (lvl == 0)      { pr = pr3; fT = fT3; W = 128; inv = 0.125f;   }
    else if (lvl == 1) { pr = pr4; fT = fT4; W = 64;  inv = 0.0625f;  }
    else               { pr = pr5; fT = fT5; W = 32;  inv = 0.03125f; }

    float x1 = __fmul_rn(pr[n*4+0], inv);
    float y1 = __fmul_rn(pr[n*4+1], inv);
    float x2 = __fmul_rn(pr[n*4+2], inv);
    float y2 = __fmul_rn(pr[n*4+3], inv);
    int c = threadIdx.x;
    #pragma unroll
    for (int si = 0; si < 7; ++si) {
        int s = blockIdx.y * 7 + si;
        int sy = s / 7, sx = s - sy * 7;
        float bx = __fdiv_rn(__fadd_rn((float)sx, 0.5f), 7.0f);
        float by = __fdiv_rn(__fadd_rn((float)sy, 0.5f), 7.0f);
        float xs = __fsub_rn(__fadd_rn(x1, __fmul_rn(bx, __fsub_rn(x2, x1))), 0.5f);
        float ys = __fsub_rn(__fadd_rn(y1, __fmul_rn(by, __fsub_rn(y2, y1))), 0.5f);
        float x0f = floorf(xs), y0f = floorf(ys);
        float wx = __fsub_rn(xs, x0f), wy = __fsub_rn(ys, y0f);
        int x0i = min(max((int)x0f, 0), W - 1);
        int x1i = min(x0i + 1, W - 1);
        int y0i = min(max((int)y0f, 0), W - 1);
        int y1i = min(y0i + 1, W - 1);
        const float* b00 = fT + (size_t)(y0i * W + x0i) * CCH;
        const float* b01 = fT + (size_t)(y0i * W + x1i) * CCH;
        const float* b10 = fT + (size_t)(y1i * W + x0i) * CCH;
        const float* b11 = fT + (size_t)(y1i * W + x1i) * CCH;
        float v00 = b00[c], v01 = b01[c], v10 = b10[c], v11 = b11[c];
        float omwx = __fsub_rn(1.0f, wx), omwy = __fsub_rn(1.0f, wy);
        float top = __fadd_rn(__fmul_rn(omwx, v00), __fmul_rn(wx, v01));
        float bot = __fadd_rn(__fmul_rn(omwx, v10), __fmul_rn(wx, v11));
        float val = __fadd_rn(__fmul_rn(omwy, top), __fmul_rn(wy, bot));
        f16 h = (f16)val;
        f16 l = (f16)(__fsub_rn(val, (float)h) * L2SCALE);
        size_t idx = (size_t)m * KDIM + s * CCH + c;   // k' = s*256 + c
        Ah[idx] = h;
        Al[idx] = l;
    }
}

// ---------------- B transpose + fp16 split (perm baked for w1) ----------------
template<int PERM>
__global__ __launch_bounds__(256) void k_splitT(const float* __restrict__ Bin,
                                                f16* __restrict__ BhT, f16* __restrict__ BlT,
                                                int K)
{
    __shared__ float t[64][65];
    int kb = blockIdx.x * 64;
    int nb = blockIdx.y * 64;
    int tid = threadIdx.x;
    int x = tid & 63, y4 = tid >> 6;
    #pragma unroll
    for (int i = 0; i < 16; ++i) {
        int r = y4 + i * 4;           // local k index
        int kk = kb + r;
        int row = PERM ? ((kk & 255) * 49 + (kk >> 8)) : kk;
        t[r][x] = Bin[(size_t)row * 1024 + nb + x];
    }
    __syncthreads();
    #pragma unroll
    for (int i = 0; i < 16; ++i) {
        int r = y4 + i * 4;           // local n index
        float v = t[x][r];
        f16 h = (f16)v;
        f16 l = (f16)(__fsub_rn(v, (float)h) * L2SCALE);
        size_t o = (size_t)(nb + r) * K + kb + x;
        BhT[o] = h;
        BlT[o] = l;
    }
}

// ---------------- MFMA emulated-fp32 GEMM ----------------
// tile 128x64, per-wave 64x32, K-step 32, register-prefetch, ragged split-K.
// C = Ah*Bh + 2^-11 (Ah*Bl' + Al'*Bh)
template<int SPLITK>
__global__ __launch_bounds__(256, 3) void k_gemm_mfma(
    const f16* __restrict__ Ah, const f16* __restrict__ Al,
    const f16* __restrict__ BhT, const f16* __restrict__ BlT,
    float* __restrict__ Cp, int K)
{
    __shared__ f16 sAh[128 * LDSPAD];
    __shared__ f16 sAl[128 * LDSPAD];
    __shared__ f16 sBh[64 * LDSPAD];
    __shared__ f16 sBl[64 * LDSPAD];
    const int bm = blockIdx.x * 128;
    const int bn = blockIdx.y * 64;
    const int S = K >> 5;
    const int kb = S / SPLITK, krem = S - kb * SPLITK;
    const int z = blockIdx.z;
    const int s0 = z * kb + min(z, krem);
    const int ns = kb + (z < krem ? 1 : 0);
    const int kbeg = s0 << 5;
    const int tid = threadIdx.x;
    const int lane = tid & 63;
    const int wid = tid >> 6;           // 4 waves: wr in {0,1} x wc in {0,1}
    const int wr = wid >> 1, wc = wid & 1;
    const int lr = lane & 15;
    const int kg = lane >> 4;           // 0..3

    const int ar = tid >> 2;            // 0..63
    const int ao = (tid & 3) * 8;       // 0,8,16,24

    f32x4 acc1[4][2], acc2[4][2];
    #pragma unroll
    for (int i = 0; i < 4; ++i) {
        #pragma unroll
        for (int j = 0; j < 2; ++j) {
            acc1[i][j] = (f32x4)0.f;
            acc2[i][j] = (f32x4)0.f;
        }
    }

    const f16* gAh0 = Ah  + (size_t)(bm + ar) * K + ao;
    const f16* gAh1 = Ah  + (size_t)(bm + 64 + ar) * K + ao;
    const f16* gAl0 = Al  + (size_t)(bm + ar) * K + ao;
    const f16* gAl1 = Al  + (size_t)(bm + 64 + ar) * K + ao;
    const f16* gBh  = BhT + (size_t)(bn + ar) * K + ao;
    const f16* gBl  = BlT + (size_t)(bn + ar) * K + ao;

    // prefetch tile 0
    float4 va0 = *(const float4*)(gAh0 + kbeg);
    float4 va1 = *(const float4*)(gAh1 + kbeg);
    float4 vb0 = *(const float4*)(gAl0 + kbeg);
    float4 vb1 = *(const float4*)(gAl1 + kbeg);
    float4 vc  = *(const float4*)(gBh  + kbeg);
    float4 vd  = *(const float4*)(gBl  + kbeg);

    for (int ks = 0; ks < ns; ++ks) {
        __syncthreads();   // previous iteration's fragment reads complete
        *(float4*)&sAh[ar * LDSPAD + ao]        = va0;
        *(float4*)&sAh[(64 + ar) * LDSPAD + ao] = va1;
        *(float4*)&sAl[ar * LDSPAD + ao]        = vb0;
        *(float4*)&sAl[(64 + ar) * LDSPAD + ao] = vb1;
        *(float4*)&sBh[ar * LDSPAD + ao]        = vc;
        *(float4*)&sBl[ar * LDSPAD + ao]        = vd;
        __syncthreads();
        if (ks + 1 < ns) {   // issue next-tile loads BEFORE MFMA phase
            int k1 = kbeg + ((ks + 1) << 5);
            va0 = *(const float4*)(gAh0 + k1);
            va1 = *(const float4*)(gAh1 + k1);
            vb0 = *(const float4*)(gAl0 + k1);
            vb1 = *(const float4*)(gAl1 + k1);
            vc  = *(const float4*)(gBh  + k1);
            vd  = *(const float4*)(gBl  + k1);
        }
        f16x8 bh[2], bl[2];
        #pragma unroll
        for (int fj = 0; fj < 2; ++fj) {
            bh[fj] = *(const f16x8*)&sBh[(wc * 32 + fj * 16 + lr) * LDSPAD + kg * 8];
            bl[fj] = *(const f16x8*)&sBl[(wc * 32 + fj * 16 + lr) * LDSPAD + kg * 8];
        }
        #pragma unroll
        for (int fi = 0; fi < 4; ++fi) {
            f16x8 ah = *(const f16x8*)&sAh[(wr * 64 + fi * 16 + lr) * LDSPAD + kg * 8];
            f16x8 al = *(const f16x8*)&sAl[(wr * 64 + fi * 16 + lr) * LDSPAD + kg * 8];
            #pragma unroll
            for (int fj = 0; fj < 2; ++fj) {
                acc2[fi][fj] = __builtin_amdgcn_mfma_f32_16x16x32_f16(al, bh[fj], acc2[fi][fj], 0, 0, 0);
                acc2[fi][fj] = __builtin_amdgcn_mfma_f32_16x16x32_f16(ah, bl[fj], acc2[fi][fj], 0, 0, 0);
                acc1[fi][fj] = __builtin_amdgcn_mfma_f32_16x16x32_f16(ah, bh[fj], acc1[fi][fj], 0, 0, 0);
            }
        }
    }

    float* Cb = Cp + (size_t)z * 3072 * 1024;
    #pragma unroll
    for (int fi = 0; fi < 4; ++fi) {
        #pragma unroll
        for (int fj = 0; fj < 2; ++fj) {
            #pragma unroll
            for (int r = 0; r < 4; ++r) {
                int row = bm + wr * 64 + fi * 16 + kg * 4 + r;
                int col = bn + wc * 32 + fj * 16 + lr;
                Cb[(size_t)row * 1024 + col] = acc1[fi][fj][r] + L2INV * acc2[fi][fj][r];
            }
        }
    }
}

// ---------------- split-K reduce + bias + relu -> fp16 h/l splits (FC1) ----------------
template<int SPLITK>
__global__ __launch_bounds__(256) void k_reduce_split(
    const float* __restrict__ Cp, const float* __restrict__ bias,
    f16* __restrict__ Hh, f16* __restrict__ Hl)
{
    size_t base = ((size_t)blockIdx.x * 256 + threadIdx.x) * 4;
    int col = (int)(base & 1023);
    float4 s = *(const float4*)(Cp + base);
    #pragma unroll
    for (int zz = 1; zz < SPLITK; ++zz) {
        float4 p = *(const float4*)(Cp + (size_t)zz * 3072 * 1024 + base);
        s.x += p.x; s.y += p.y; s.z += p.z; s.w += p.w;
    }
    float4 b = *(const float4*)(bias + col);
    float o[4];
    o[0] = fmaxf(s.x + b.x, 0.f); o[1] = fmaxf(s.y + b.y, 0.f);
    o[2] = fmaxf(s.z + b.z, 0.f); o[3] = fmaxf(s.w + b.w, 0.f);
    f16x4 hv, lv;
    #pragma unroll
    for (int j = 0; j < 4; ++j) {
        f16 h = (f16)o[j];
        hv[j] = h;
        lv[j] = (f16)(__fsub_rn(o[j], (float)h) * L2SCALE);
    }
    *(f16x4*)(Hh + base) = hv;
    *(f16x4*)(Hl + base) = lv;
}

// ---------------- split-K reduce + bias + relu -> fp32 (FC2) ----------------
template<int SPLITK>
__global__ __launch_bounds__(256) void k_reduce_f32(
    const float* __restrict__ Cp, const float* __restrict__ bias, float* __restrict__ H)
{
    size_t base = ((size_t)blockIdx.x * 256 + threadIdx.x) * 4;
    int col = (int)(base & 1023);
    float4 s = *(const float4*)(Cp + base);
    #pragma unroll
    for (int zz = 1; zz < SPLITK; ++zz) {
        float4 p = *(const float4*)(Cp + (size_t)zz * 3072 * 1024 + base);
        s.x += p.x; s.y += p.y; s.z += p.z; s.w += p.w;
    }
    float4 b = *(const float4*)(bias + col);
    float4 o;
    o.x = fmaxf(s.x + b.x, 0.f); o.y = fmaxf(s.y + b.y, 0.f);
    o.z = fmaxf(s.z + b.z, 0.f); o.w = fmaxf(s.w + b.w, 0.f);
    *(float4*)(H + base) = o;
}

// ---------------- wc (1024x20) -> wcT (20x1024) ----------------
__global__ __launch_bounds__(256) void k_wct(const float* __restrict__ wc, float* __restrict__ wcT)
{
    int t = blockIdx.x * 256 + threadIdx.x;
    if (t >= NCLS * 1024) return;
    int k = t & 1023, c = t >> 10;
    wcT[t] = wc[k * NCLS + c];
}

// ---------------- classifier head: wave-parallel dot products (fp32) ----------------
__global__ __launch_bounds__(256) void k_head2(
    const float* __restrict__ h2, const float* __restrict__ wcT, const float* __restrict__ bc,
    float* __restrict__ scores, float* __restrict__ classesF)
{
    __shared__ float hrow[1024];
    __shared__ float probs[NCLS];
    int m = blockIdx.x, tid = threadIdx.x;
    *(float4*)&hrow[tid << 2] = *(const float4*)(h2 + (size_t)m * 1024 + (tid << 2));
    __syncthreads();
    int w = tid >> 6, lane = tid & 63;
    for (int cg = 0; cg < 5; ++cg) {
        int cls = w * 5 + cg;
        float acc = 0.f;
        #pragma unroll
        for (int j = 0; j < 16; ++j) {
            int k = lane + 64 * j;
            acc = fmaf(hrow[k], wcT[cls * 1024 + k], acc);
        }
        #pragma unroll
        for (int off = 32; off > 0; off >>= 1)
            acc += __shfl_down(acc, off);
        if (lane == 0) {
            float logit = __fadd_rn(acc, bc[cls]);
            probs[cls] = __fdiv_rn(1.0f, __fadd_rn(1.0f, expf(-logit)));
        }
    }
    __syncthreads();
    if (tid == 0) {
        float best = -1.0f; int bi = 0;
        for (int n2 = 0; n2 < NCLS; ++n2) {
            float p = probs[n2];
            if (p > best) { best = p; bi = n2; }
        }
        scores[m] = best;
        classesF[m] = (float)bi;
    }
}

// ---------------- global max over all box coords ----------------
__global__ __launch_bounds__(1024) void k_boxmax(const float* __restrict__ a,
                                                 const float* __restrict__ b,
                                                 const float* __restrict__ c,
                                                 float* __restrict__ maxv)
{
    __shared__ float red[1024];
    int tid = threadIdx.x;
    float v = -1e30f;
    for (int i = tid; i < 4000; i += 1024) {
        v = fmaxf(v, a[i]); v = fmaxf(v, b[i]); v = fmaxf(v, c[i]);
    }
    red[tid] = v; __syncthreads();
    for (int s = 512; s > 0; s >>= 1) {
        if (tid < s) red[tid] = fmaxf(red[tid], red[tid + s]);
        __syncthreads();
    }
    if (tid == 0) maxv[0] = red[0];
}

// ---------------- per-box class-offset box + area ----------------
__global__ __launch_bounds__(256) void k_prep(
    const float* __restrict__ pr3, const float* __restrict__ pr4, const float* __restrict__ pr5,
    const float* __restrict__ classesF, const float* __restrict__ maxv,
    float* __restrict__ obox, float* __restrict__ area)
{
    int i = blockIdx.x * 256 + threadIdx.x;
    if (i >= NBOX) return;
    int lvl = i / 1000, n = i - lvl * 1000;
    const float* pr = lvl == 0 ? pr3 : (lvl == 1 ? pr4 : pr5);
    float off = __fmul_rn(classesF[i], __fadd_rn(maxv[0], 1.0f));
    float b0 = __fadd_rn(pr[n*4+0], off);
    float b1 = __fadd_rn(pr[n*4+1], off);
    float b2 = __fadd_rn(pr[n*4+2], off);
    float b3 = __fadd_rn(pr[n*4+3], off);
    obox[i*4+0] = b0; obox[i*4+1] = b1; obox[i*4+2] = b2; obox[i*4+3] = b3;
    area[i] = __fmul_rn(fmaxf(__fsub_rn(b2, b0), 0.f), fmaxf(__fsub_rn(b3, b1), 0.f));
}

// ---------------- bitonic argsort (score desc, idx asc == stable argsort(-s)) ----------------
__global__ __launch_bounds__(1024) void k_sort(const float* __restrict__ scores,
                                               int* __restrict__ ord, float* __restrict__ ssort)
{
    __shared__ float ss[4096];
    __shared__ int   si[4096];
    int tid = threadIdx.x;
    for (int t = tid; t < 4096; t += 1024) {
        if (t < NBOX) { ss[t] = scores[t]; si[t] = t; }
        else          { ss[t] = -__builtin_inff(); si[t] = t; }
    }
    __syncthreads();
    for (int k = 2; k <= 4096; k <<= 1) {
        for (int j = k >> 1; j > 0; j >>= 1) {
            for (int t = tid; t < 4096; t += 1024) {
                int l = t ^ j;
                if (l > t) {
                    float st = ss[t], sl = ss[l];
                    int it = si[t], il = si[l];
                    bool up = ((t & k) == 0);
                    bool lLessT = (sl > st) || (sl == st && il < it);
                    if (lLessT == up) { ss[t] = sl; ss[l] = st; si[t] = il; si[l] = it; }
                }
            }
            __syncthreads();
        }
    }
    for (int t = tid; t < NBOX; t += 1024) { ord[t] = si[t]; ssort[t] = ss[t]; }
}

// ---------------- suppression bitmask ----------------
__global__ __launch_bounds__(256) void k_sup(
    const int* __restrict__ ord, const float* __restrict__ obox, const float* __restrict__ area,
    u64* __restrict__ sup)
{
    int i = blockIdx.x;
    int w = blockIdx.y * 4 + (threadIdx.x >> 6);
    int lane = threadIdx.x & 63;
    if (w >= NW) return;
    int j = (w << 6) + lane;
    bool s = false;
    int oi = ord[i];
    float bi0 = obox[oi*4+0], bi1 = obox[oi*4+1], bi2 = obox[oi*4+2], bi3 = obox[oi*4+3];
    float ai = area[oi];
    if (j > i && j < NBOX) {
        int oj = ord[j];
        float bj0 = obox[oj*4+0], bj1 = obox[oj*4+1], bj2 = obox[oj*4+2], bj3 = obox[oj*4+3];
        float lt0 = fmaxf(bi0, bj0), lt1 = fmaxf(bi1, bj1);
        float rb0 = fminf(bi2, bj2), rb1 = fminf(bi3, bj3);
        float w0 = fmaxf(__fsub_rn(rb0, lt0), 0.f), w1 = fmaxf(__fsub_rn(rb1, lt1), 0.f);
        float inter = __fmul_rn(w0, w1);
        float den = __fadd_rn(__fsub_rn(__fadd_rn(ai, area[oj]), inter), 1e-8f);
        float iou = __fdiv_rn(inter, den);
        s = iou > 0.5f;
    }
    u64 mask = __ballot(s);
    if (lane == 0) sup[(size_t)i * NW + w] = mask;
}

// ---------------- NMS scan: chunked, double-buffered LDS ----------------
__global__ __launch_bounds__(256) void k_nms2(
    const float* __restrict__ ssort, const u64* __restrict__ sup, u64* __restrict__ rem)
{
    __shared__ u64 buf[2][64 * NW];
    int tid = threadIdx.x;
    int lane = tid & 63;
    u64 r = 0;
    if (tid < NW) {
        for (int b = 0; b < 64; ++b) {
            int idx = (tid << 6) + b;
            if (idx < NBOX && ssort[idx] >= 0.05f) r |= (1ull << b);
        }
    }
    for (int t = tid; t < 64 * NW; t += 256) buf[0][t] = sup[t];
    __syncthreads();
    const int NCHUNK = (NBOX + 63) >> 6;   // 47
    for (int c = 0; c < NCHUNK; ++c) {
        int cur = c & 1;
        if (c + 1 < NCHUNK) {
            size_t base = (size_t)(c + 1) * 64 * NW;
            for (int t = tid; t < 64 * NW; t += 256)
                if (base + t < (size_t)NBOX * NW) buf[cur ^ 1][t] = sup[base + t];
        }
        if (tid < 64) {
            for (int b = 0; b < 64; ++b) {
                int i = (c << 6) + b;
                if (i >= NBOX) break;
                unsigned lo = __shfl((unsigned)(r & 0xffffffffull), c);
                unsigned hi = __shfl((unsigned)(r >> 32), c);
                u64 wv = ((u64)hi << 32) | lo;
                if ((wv >> b) & 1ull) {
                    if (lane < NW) r &= ~buf[cur][b * NW + lane];
                }
            }
        }
        __syncthreads();
    }
    if (tid < NW) rem[tid] = r;
}

// ---------------- final output assembly ----------------
__global__ __launch_bounds__(256) void k_out(
    const float* __restrict__ pr3, const float* __restrict__ pr4, const float* __restrict__ pr5,
    const float* __restrict__ classesF, const float* __restrict__ scores,
    const int* __restrict__ ord, const u64* __restrict__ rem, float* __restrict__ out)
{
    int t = blockIdx.x * 256 + threadIdx.x;
    if (t >= 21000) return;
    if (t < 12000) {
        int m = t >> 2, j = t & 3;
        int lvl = m / 1000, n = m - lvl * 1000;
        const float* pr = lvl == 0 ? pr3 : (lvl == 1 ? pr4 : pr5);
        out[t] = pr[n*4 + j];
    } else if (t < 15000) {
        out[t] = classesF[t - 12000];
    } else if (t < 18000) {
        out[t] = scores[t - 15000];
    } else {
        int p = t - 18000;
        int orig = ord[p];
        int bit = (int)((rem[p >> 6] >> (p & 63)) & 1ull);
        out[18000 + orig] = (float)bit;
    }
}

extern "C" void kernel_launch(void* const* d_in, const int* in_sizes, int n_in,
                              void* d_out, int out_size, void* d_ws, size_t ws_size,
                              hipStream_t stream)
{
    const float* p3  = (const float*)d_in[0];
    const float* p4  = (const float*)d_in[1];
    const float* p5  = (const float*)d_in[2];
    const float* pr3 = (const float*)d_in[3];
    const float* pr4 = (const float*)d_in[4];
    const float* pr5 = (const float*)d_in[5];
    const float* w1  = (const float*)d_in[6];
    const float* b1  = (const float*)d_in[7];
    const float* w2  = (const float*)d_in[8];
    const float* b2  = (const float*)d_in[9];
    const float* wc  = (const float*)d_in[10];
    const float* bc  = (const float*)d_in[11];

    float* ws    = (float*)d_ws;
    float* Cp    = ws + OFF_CP;
    float* fT3   = ws + OFF_FT3;
    float* fT4   = ws + OFF_FT4;
    float* fT5   = ws + OFF_FT5;
    f16*   Ah    = (f16*)(ws + OFF_AH);
    f16*   Al    = (f16*)(ws + OFF_AL);
    f16*   B1hT  = (f16*)(ws + OFF_B1HT);
    f16*   B1lT  = (f16*)(ws + OFF_B1LT);
    f16*   B2hT  = (f16*)(ws + OFF_B2HT);
    f16*   B2lT  = (f16*)(ws + OFF_B2LT);
    f16*   H1h   = (f16*)(ws + OFF_H1H);
    f16*   H1l   = (f16*)(ws + OFF_H1L);
    float* h2    = ws + OFF_H2;
    float* sc    = ws + OFF_SC;
    float* clf   = ws + OFF_CL;
    float* maxv  = ws + OFF_MAXV;
    float* obox  = ws + OFF_OBOX;
    float* area  = ws + OFF_AREA;
    int*   ord   = (int*)(ws + OFF_ORD);
    float* ssort = ws + OFF_SSORT;
    u64*   sup   = (u64*)(ws + OFF_SUP);
    u64*   rem   = (u64*)(ws + OFF_REM);
    float* wcT   = ws + OFF_WCT;
    float* out   = (float*)d_out;

    // ---- phase 1: prep (FT lives inside Cp space; dead before GEMM writes Cp) ----
    k_transpose2<<<dim3(256, 4), 256, 0, stream>>>(p3, fT3, 128 * 128);
    k_transpose2<<<dim3(64, 4),  256, 0, stream>>>(p4, fT4, 64 * 64);
    k_transpose2<<<dim3(16, 4),  256, 0, stream>>>(p5, fT5, 32 * 32);
    k_roialign2<<<dim3(NBOX, 7), 256, 0, stream>>>(fT3, fT4, fT5, pr3, pr4, pr5, Ah, Al);
    k_splitT<1><<<dim3(KDIM / 64, 16), 256, 0, stream>>>(w1, B1hT, B1lT, KDIM);
    k_splitT<0><<<dim3(16, 16), 256, 0, stream>>>(w2, B2hT, B2lT, 1024);

    // ---- phase 2: GEMMs (H1/H2 alias dead B1 region) ----
    k_gemm_mfma<3><<<dim3(24, 16, 3), 256, 0, stream>>>(Ah, Al, B1hT, B1lT, Cp, KDIM);
    k_reduce_split<3><<<3072, 256, 0, stream>>>(Cp, b1, H1h, H1l);
    k_gemm_mfma<3><<<dim3(24, 16, 3), 256, 0, stream>>>(H1h, H1l, B2hT, B2lT, Cp, 1024);
    k_reduce_f32<3><<<3072, 256, 0, stream>>>(Cp, b2, h2);

    // ---- phase 3: head + NMS (smalls alias dead B1lT region -> must run after GEMM1) ----
    k_wct<<<(NCLS * 1024 + 255) / 256, 256, 0, stream>>>(wc, wcT);
    k_boxmax<<<1, 1024, 0, stream>>>(pr3, pr4, pr5, maxv);
    k_head2<<<NBOX, 256, 0, stream>>>(h2, wcT, bc, sc, clf);
    k_prep<<<12, 256, 0, stream>>>(pr3, pr4, pr5, clf, maxv, obox, area);
    k_sort<<<1, 1024, 0, stream>>>(sc, ord, ssort);
    k_sup<<<dim3(NBOX, 12), 256, 0, stream>>>(ord, obox, area, sup);
    k_nms2<<<1, 256, 0, stream>>>(ssort, sup, rem);
    k_out<<<(21000 + 255) / 256, 256, 0, stream>>>(pr3, pr4, pr5, clf, sc, ord, rem, out);
}

// Round 8
// 882.778 us; speedup vs baseline: 2.8307x; 1.3222x over previous
//
#include <hip/hip_runtime.h>
#include <cstdint>

typedef unsigned long long u64;
typedef _Float16 f16;
typedef _Float16 f16x4 __attribute__((ext_vector_type(4)));
typedef _Float16 f16x8 __attribute__((ext_vector_type(8)));
typedef float f32x4 __attribute__((ext_vector_type(4)));

#define NBOX 3000
#define CCH  256
#define KDIM 12544   // 256*49
#define NCLS 20
#define NW   47      // ceil(3000/64) u64 words
#define L2SCALE 2048.0f          // 2^11
#define L2INV   4.8828125e-4f    // 2^-11
#define LDSPAD 40                // f16 row stride in LDS (80B -> conflict-light frag reads)

// ---------------- workspace layout (float offsets), aliased by liveness ----------------
static constexpr size_t OFF_CP   = 0;            // 3 x 3072 x 1024 f32 = 9,437,184 floats
static constexpr size_t OFF_FT3  = 0;            //   alias in Cp (dead before GEMM)
static constexpr size_t OFF_FT4  = 4194304;
static constexpr size_t OFF_FT5  = 5242880;      //   ends 5,505,024 < 9,437,184
static constexpr size_t OFF_AH   = 9437184;      // 3072x12544 f16
static constexpr size_t OFF_AL   = 28704768;     // ends 47,972,352
static constexpr size_t OFF_B1HT = 47972352;     // 1024x12544 f16
static constexpr size_t OFF_B1LT = 54394880;     // ends 60,817,408
// --- aliases valid only AFTER GEMM1 (B1 dead): ---
static constexpr size_t OFF_H1H  = 47972352;
static constexpr size_t OFF_H1L  = 49545216;
static constexpr size_t OFF_H2   = 51118080;     // ends 54,263,808
static constexpr size_t OFF_SC   = 54394880;
static constexpr size_t OFF_CL   = 54397952;
static constexpr size_t OFF_MAXV = 54401024;
static constexpr size_t OFF_OBOX = 54401088;
static constexpr size_t OFF_AREA = 54413120;
static constexpr size_t OFF_ORD  = 54416128;     // int
static constexpr size_t OFF_SSORT= 54419200;
static constexpr size_t OFF_SUP  = 54422272;     // u64[3000*47]
static constexpr size_t OFF_REM  = 54704272;     // u64[47]
static constexpr size_t OFF_WCT  = 54704384;     // ends 54,724,864
// --- end aliases ---
static constexpr size_t OFF_B2HT = 60817408;
static constexpr size_t OFF_B2LT = 61341696;     // ends 61,865,984
// total = 61,865,984 floats = 247.46 MB

// ---------------- CHW -> HWC transpose, LDS-tiled 64x64 ----------------
__global__ __launch_bounds__(256) void k_transpose2(const float* __restrict__ in,
                                                    float* __restrict__ out, int HW)
{
    __shared__ float t[64][65];
    int pb = blockIdx.x * 64;
    int cb = blockIdx.y * 64;
    int tid = threadIdx.x;
    int x = tid & 63, y4 = tid >> 6;
    #pragma unroll
    for (int i = 0; i < 16; ++i) {
        int cr = y4 + i * 4;
        t[x][cr] = in[(size_t)(cb + cr) * HW + pb + x];
    }
    __syncthreads();
    #pragma unroll
    for (int i = 0; i < 16; ++i) {
        int pr = y4 + i * 4;
        out[(size_t)(pb + pr) * CCH + cb + x] = t[pr][x];
    }
}

// ---------------- ROI align: block = (box, 7-sample group); writes fp16 h/l splits ----------------
__global__ __launch_bounds__(256) void k_roialign2(
    const float* __restrict__ fT3, const float* __restrict__ fT4, const float* __restrict__ fT5,
    const float* __restrict__ pr3, const float* __restrict__ pr4, const float* __restrict__ pr5,
    f16* __restrict__ Ah, f16* __restrict__ Al)
{
    int m = blockIdx.x;
    int lvl = m / 1000, n = m - lvl * 1000;
    const float* pr; const float* fT; int W; float inv;
    if (lvl == 0)      { pr = pr3; fT = fT3; W = 128; inv = 0.125f;   }
    else if (lvl == 1) { pr = pr4; fT = fT4; W = 64;  inv = 0.0625f;  }
    else               { pr = pr5; fT = fT5; W = 32;  inv = 0.03125f; }

    float x1 = __fmul_rn(pr[n*4+0], inv);
    float y1 = __fmul_rn(pr[n*4+1], inv);
    float x2 = __fmul_rn(pr[n*4+2], inv);
    float y2 = __fmul_rn(pr[n*4+3], inv);
    int c = threadIdx.x;
    #pragma unroll
    for (int si = 0; si < 7; ++si) {
        int s = blockIdx.y * 7 + si;
        int sy = s / 7, sx = s - sy * 7;
        float bx = __fdiv_rn(__fadd_rn((float)sx, 0.5f), 7.0f);
        float by = __fdiv_rn(__fadd_rn((float)sy, 0.5f), 7.0f);
        float xs = __fsub_rn(__fadd_rn(x1, __fmul_rn(bx, __fsub_rn(x2, x1))), 0.5f);
        float ys = __fsub_rn(__fadd_rn(y1, __fmul_rn(by, __fsub_rn(y2, y1))), 0.5f);
        float x0f = floorf(xs), y0f = floorf(ys);
        float wx = __fsub_rn(xs, x0f), wy = __fsub_rn(ys, y0f);
        int x0i = min(max((int)x0f, 0), W - 1);
        int x1i = min(x0i + 1, W - 1);
        int y0i = min(max((int)y0f, 0), W - 1);
        int y1i = min(y0i + 1, W - 1);
        const float* b00 = fT + (size_t)(y0i * W + x0i) * CCH;
        const float* b01 = fT + (size_t)(y0i * W + x1i) * CCH;
        const float* b10 = fT + (size_t)(y1i * W + x0i) * CCH;
        const float* b11 = fT + (size_t)(y1i * W + x1i) * CCH;
        float v00 = b00[c], v01 = b01[c], v10 = b10[c], v11 = b11[c];
        float omwx = __fsub_rn(1.0f, wx), omwy = __fsub_rn(1.0f, wy);
        float top = __fadd_rn(__fmul_rn(omwx, v00), __fmul_rn(wx, v01));
        float bot = __fadd_rn(__fmul_rn(omwx, v10), __fmul_rn(wx, v11));
        float val = __fadd_rn(__fmul_rn(omwy, top), __fmul_rn(wy, bot));
        f16 h = (f16)val;
        f16 l = (f16)(__fsub_rn(val, (float)h) * L2SCALE);
        size_t idx = (size_t)m * KDIM + s * CCH + c;   // k' = s*256 + c
        Ah[idx] = h;
        Al[idx] = l;
    }
}

// ---------------- B transpose + fp16 split (perm baked for w1) ----------------
template<int PERM>
__global__ __launch_bounds__(256) void k_splitT(const float* __restrict__ Bin,
                                                f16* __restrict__ BhT, f16* __restrict__ BlT,
                                                int K)
{
    __shared__ float t[64][65];
    int kb = blockIdx.x * 64;
    int nb = blockIdx.y * 64;
    int tid = threadIdx.x;
    int x = tid & 63, y4 = tid >> 6;
    #pragma unroll
    for (int i = 0; i < 16; ++i) {
        int r = y4 + i * 4;           // local k index
        int kk = kb + r;
        int row = PERM ? ((kk & 255) * 49 + (kk >> 8)) : kk;
        t[r][x] = Bin[(size_t)row * 1024 + nb + x];
    }
    __syncthreads();
    #pragma unroll
    for (int i = 0; i < 16; ++i) {
        int r = y4 + i * 4;           // local n index
        float v = t[x][r];
        f16 h = (f16)v;
        f16 l = (f16)(__fsub_rn(v, (float)h) * L2SCALE);
        size_t o = (size_t)(nb + r) * K + kb + x;
        BhT[o] = h;
        BlT[o] = l;
    }
}

// ---------------- MFMA emulated-fp32 GEMM ----------------
// tile 128x64, per-wave 64x32, K-step 32, register-prefetch, ragged split-K.
// C = Ah*Bh + 2^-11 (Ah*Bl' + Al'*Bh)
template<int SPLITK>
__global__ __launch_bounds__(256, 3) void k_gemm_mfma(
    const f16* __restrict__ Ah, const f16* __restrict__ Al,
    const f16* __restrict__ BhT, const f16* __restrict__ BlT,
    float* __restrict__ Cp, int K)
{
    __shared__ f16 sAh[128 * LDSPAD];
    __shared__ f16 sAl[128 * LDSPAD];
    __shared__ f16 sBh[64 * LDSPAD];
    __shared__ f16 sBl[64 * LDSPAD];
    const int bm = blockIdx.x * 128;
    const int bn = blockIdx.y * 64;
    const int S = K >> 5;
    const int kb = S / SPLITK, krem = S - kb * SPLITK;
    const int z = blockIdx.z;
    const int s0 = z * kb + min(z, krem);
    const int ns = kb + (z < krem ? 1 : 0);
    const int kbeg = s0 << 5;
    const int tid = threadIdx.x;
    const int lane = tid & 63;
    const int wid = tid >> 6;           // 4 waves: wr in {0,1} x wc in {0,1}
    const int wr = wid >> 1, wc = wid & 1;
    const int lr = lane & 15;
    const int kg = lane >> 4;           // 0..3

    const int ar = tid >> 2;            // 0..63
    const int ao = (tid & 3) * 8;       // 0,8,16,24

    f32x4 acc1[4][2], acc2[4][2];
    #pragma unroll
    for (int i = 0; i < 4; ++i) {
        #pragma unroll
        for (int j = 0; j < 2; ++j) {
            acc1[i][j] = (f32x4)0.f;
            acc2[i][j] = (f32x4)0.f;
        }
    }

    const f16* gAh0 = Ah  + (size_t)(bm + ar) * K + ao;
    const f16* gAh1 = Ah  + (size_t)(bm + 64 + ar) * K + ao;
    const f16* gAl0 = Al  + (size_t)(bm + ar) * K + ao;
    const f16* gAl1 = Al  + (size_t)(bm + 64 + ar) * K + ao;
    const f16* gBh  = BhT + (size_t)(bn + ar) * K + ao;
    const f16* gBl  = BlT + (size_t)(bn + ar) * K + ao;

    // prefetch tile 0
    float4 va0 = *(const float4*)(gAh0 + kbeg);
    float4 va1 = *(const float4*)(gAh1 + kbeg);
    float4 vb0 = *(const float4*)(gAl0 + kbeg);
    float4 vb1 = *(const float4*)(gAl1 + kbeg);
    float4 vc  = *(const float4*)(gBh  + kbeg);
    float4 vd  = *(const float4*)(gBl  + kbeg);

    for (int ks = 0; ks < ns; ++ks) {
        __syncthreads();   // previous iteration's fragment reads complete
        *(float4*)&sAh[ar * LDSPAD + ao]        = va0;
        *(float4*)&sAh[(64 + ar) * LDSPAD + ao] = va1;
        *(float4*)&sAl[ar * LDSPAD + ao]        = vb0;
        *(float4*)&sAl[(64 + ar) * LDSPAD + ao] = vb1;
        *(float4*)&sBh[ar * LDSPAD + ao]        = vc;
        *(float4*)&sBl[ar * LDSPAD + ao]        = vd;
        __syncthreads();
        if (ks + 1 < ns) {   // issue next-tile loads BEFORE MFMA phase
            int k1 = kbeg + ((ks + 1) << 5);
            va0 = *(const float4*)(gAh0 + k1);
            va1 = *(const float4*)(gAh1 + k1);
            vb0 = *(const float4*)(gAl0 + k1);
            vb1 = *(const float4*)(gAl1 + k1);
            vc  = *(const float4*)(gBh  + k1);
            vd  = *(const float4*)(gBl  + k1);
        }
        f16x8 bh[2], bl[2];
        #pragma unroll
        for (int fj = 0; fj < 2; ++fj) {
            bh[fj] = *(const f16x8*)&sBh[(wc * 32 + fj * 16 + lr) * LDSPAD + kg * 8];
            bl[fj] = *(const f16x8*)&sBl[(wc * 32 + fj * 16 + lr) * LDSPAD + kg * 8];
        }
        #pragma unroll
        for (int fi = 0; fi < 4; ++fi) {
            f16x8 ah = *(const f16x8*)&sAh[(wr * 64 + fi * 16 + lr) * LDSPAD + kg * 8];
            f16x8 al = *(const f16x8*)&sAl[(wr * 64 + fi * 16 + lr) * LDSPAD + kg * 8];
            #pragma unroll
            for (int fj = 0; fj < 2; ++fj) {
                acc2[fi][fj] = __builtin_amdgcn_mfma_f32_16x16x32_f16(al, bh[fj], acc2[fi][fj], 0, 0, 0);
                acc2[fi][fj] = __builtin_amdgcn_mfma_f32_16x16x32_f16(ah, bl[fj], acc2[fi][fj], 0, 0, 0);
                acc1[fi][fj] = __builtin_amdgcn_mfma_f32_16x16x32_f16(ah, bh[fj], acc1[fi][fj], 0, 0, 0);
            }
        }
    }

    float* Cb = Cp + (size_t)z * 3072 * 1024;
    #pragma unroll
    for (int fi = 0; fi < 4; ++fi) {
        #pragma unroll
        for (int fj = 0; fj < 2; ++fj) {
            #pragma unroll
            for (int r = 0; r < 4; ++r) {
                int row = bm + wr * 64 + fi * 16 + kg * 4 + r;
                int col = bn + wc * 32 + fj * 16 + lr;
                Cb[(size_t)row * 1024 + col] = acc1[fi][fj][r] + L2INV * acc2[fi][fj][r];
            }
        }
    }
}

// ---------------- split-K reduce + bias + relu -> fp16 h/l splits (FC1) ----------------
template<int SPLITK>
__global__ __launch_bounds__(256) void k_reduce_split(
    const float* __restrict__ Cp, const float* __restrict__ bias,
    f16* __restrict__ Hh, f16* __restrict__ Hl)
{
    size_t base = ((size_t)blockIdx.x * 256 + threadIdx.x) * 4;
    int col = (int)(base & 1023);
    float4 s = *(const float4*)(Cp + base);
    #pragma unroll
    for (int zz = 1; zz < SPLITK; ++zz) {
        float4 p = *(const float4*)(Cp + (size_t)zz * 3072 * 1024 + base);
        s.x += p.x; s.y += p.y; s.z += p.z; s.w += p.w;
    }
    float4 b = *(const float4*)(bias + col);
    float o[4];
    o[0] = fmaxf(s.x + b.x, 0.f); o[1] = fmaxf(s.y + b.y, 0.f);
    o[2] = fmaxf(s.z + b.z, 0.f); o[3] = fmaxf(s.w + b.w, 0.f);
    f16x4 hv, lv;
    #pragma unroll
    for (int j = 0; j < 4; ++j) {
        f16 h = (f16)o[j];
        hv[j] = h;
        lv[j] = (f16)(__fsub_rn(o[j], (float)h) * L2SCALE);
    }
    *(f16x4*)(Hh + base) = hv;
    *(f16x4*)(Hl + base) = lv;
}

// ---------------- split-K reduce + bias + relu -> fp32 (FC2) ----------------
template<int SPLITK>
__global__ __launch_bounds__(256) void k_reduce_f32(
    const float* __restrict__ Cp, const float* __restrict__ bias, float* __restrict__ H)
{
    size_t base = ((size_t)blockIdx.x * 256 + threadIdx.x) * 4;
    int col = (int)(base & 1023);
    float4 s = *(const float4*)(Cp + base);
    #pragma unroll
    for (int zz = 1; zz < SPLITK; ++zz) {
        float4 p = *(const float4*)(Cp + (size_t)zz * 3072 * 1024 + base);
        s.x += p.x; s.y += p.y; s.z += p.z; s.w += p.w;
    }
    float4 b = *(const float4*)(bias + col);
    float4 o;
    o.x = fmaxf(s.x + b.x, 0.f); o.y = fmaxf(s.y + b.y, 0.f);
    o.z = fmaxf(s.z + b.z, 0.f); o.w = fmaxf(s.w + b.w, 0.f);
    *(float4*)(H + base) = o;
}

// ---------------- wc (1024x20) -> wcT (20x1024) ----------------
__global__ __launch_bounds__(256) void k_wct(const float* __restrict__ wc, float* __restrict__ wcT)
{
    int t = blockIdx.x * 256 + threadIdx.x;
    if (t >= NCLS * 1024) return;
    int k = t & 1023, c = t >> 10;
    wcT[t] = wc[k * NCLS + c];
}

// ---------------- classifier head: wave-parallel dot products (fp32) ----------------
__global__ __launch_bounds__(256) void k_head2(
    const float* __restrict__ h2, const float* __restrict__ wcT, const float* __restrict__ bc,
    float* __restrict__ scores, float* __restrict__ classesF)
{
    __shared__ float hrow[1024];
    __shared__ float probs[NCLS];
    int m = blockIdx.x, tid = threadIdx.x;
    *(float4*)&hrow[tid << 2] = *(const float4*)(h2 + (size_t)m * 1024 + (tid << 2));
    __syncthreads();
    int w = tid >> 6, lane = tid & 63;
    for (int cg = 0; cg < 5; ++cg) {
        int cls = w * 5 + cg;
        float acc = 0.f;
        #pragma unroll
        for (int j = 0; j < 16; ++j) {
            int k = lane + 64 * j;
            acc = fmaf(hrow[k], wcT[cls * 1024 + k], acc);
        }
        #pragma unroll
        for (int off = 32; off > 0; off >>= 1)
            acc += __shfl_down(acc, off);
        if (lane == 0) {
            float logit = __fadd_rn(acc, bc[cls]);
            probs[cls] = __fdiv_rn(1.0f, __fadd_rn(1.0f, expf(-logit)));
        }
    }
    __syncthreads();
    if (tid == 0) {
        float best = -1.0f; int bi = 0;
        for (int n2 = 0; n2 < NCLS; ++n2) {
            float p = probs[n2];
            if (p > best) { best = p; bi = n2; }
        }
        scores[m] = best;
        classesF[m] = (float)bi;
    }
}

// ---------------- global max over all box coords ----------------
__global__ __launch_bounds__(1024) void k_boxmax(const float* __restrict__ a,
                                                 const float* __restrict__ b,
                                                 const float* __restrict__ c,
                                                 float* __restrict__ maxv)
{
    __shared__ float red[1024];
    int tid = threadIdx.x;
    float v = -1e30f;
    for (int i = tid; i < 4000; i += 1024) {
        v = fmaxf(v, a[i]); v = fmaxf(v, b[i]); v = fmaxf(v, c[i]);
    }
    red[tid] = v; __syncthreads();
    for (int s = 512; s > 0; s >>= 1) {
        if (tid < s) red[tid] = fmaxf(red[tid], red[tid + s]);
        __syncthreads();
    }
    if (tid == 0) maxv[0] = red[0];
}

// ---------------- per-box class-offset box + area ----------------
__global__ __launch_bounds__(256) void k_prep(
    const float* __restrict__ pr3, const float* __restrict__ pr4, const float* __restrict__ pr5,
    const float* __restrict__ classesF, const float* __restrict__ maxv,
    float* __restrict__ obox, float* __restrict__ area)
{
    int i = blockIdx.x * 256 + threadIdx.x;
    if (i >= NBOX) return;
    int lvl = i / 1000, n = i - lvl * 1000;
    const float* pr = lvl == 0 ? pr3 : (lvl == 1 ? pr4 : pr5);
    float off = __fmul_rn(classesF[i], __fadd_rn(maxv[0], 1.0f));
    float b0 = __fadd_rn(pr[n*4+0], off);
    float b1 = __fadd_rn(pr[n*4+1], off);
    float b2 = __fadd_rn(pr[n*4+2], off);
    float b3 = __fadd_rn(pr[n*4+3], off);
    obox[i*4+0] = b0; obox[i*4+1] = b1; obox[i*4+2] = b2; obox[i*4+3] = b3;
    area[i] = __fmul_rn(fmaxf(__fsub_rn(b2, b0), 0.f), fmaxf(__fsub_rn(b3, b1), 0.f));
}

// ---------------- bitonic argsort (score desc, idx asc == stable argsort(-s)) ----------------
__global__ __launch_bounds__(1024) void k_sort(const float* __restrict__ scores,
                                               int* __restrict__ ord, float* __restrict__ ssort)
{
    __shared__ float ss[4096];
    __shared__ int   si[4096];
    int tid = threadIdx.x;
    for (int t = tid; t < 4096; t += 1024) {
        if (t < NBOX) { ss[t] = scores[t]; si[t] = t; }
        else          { ss[t] = -__builtin_inff(); si[t] = t; }
    }
    __syncthreads();
    for (int k = 2; k <= 4096; k <<= 1) {
        for (int j = k >> 1; j > 0; j >>= 1) {
            for (int t = tid; t < 4096; t += 1024) {
                int l = t ^ j;
                if (l > t) {
                    float st = ss[t], sl = ss[l];
                    int it = si[t], il = si[l];
                    bool up = ((t & k) == 0);
                    bool lLessT = (sl > st) || (sl == st && il < it);
                    if (lLessT == up) { ss[t] = sl; ss[l] = st; si[t] = il; si[l] = it; }
                }
            }
            __syncthreads();
        }
    }
    for (int t = tid; t < NBOX; t += 1024) { ord[t] = si[t]; ssort[t] = ss[t]; }
}

// ---------------- suppression bitmask ----------------
__global__ __launch_bounds__(256) void k_sup(
    const int* __restrict__ ord, const float* __restrict__ obox, const float* __restrict__ area,
    u64* __restrict__ sup)
{
    int i = blockIdx.x;
    int w = blockIdx.y * 4 + (threadIdx.x >> 6);
    int lane = threadIdx.x & 63;
    if (w >= NW) return;
    int j = (w << 6) + lane;
    bool s = false;
    int oi = ord[i];
    float bi0 = obox[oi*4+0], bi1 = obox[oi*4+1], bi2 = obox[oi*4+2], bi3 = obox[oi*4+3];
    float ai = area[oi];
    if (j > i && j < NBOX) {
        int oj = ord[j];
        float bj0 = obox[oj*4+0], bj1 = obox[oj*4+1], bj2 = obox[oj*4+2], bj3 = obox[oj*4+3];
        float lt0 = fmaxf(bi0, bj0), lt1 = fmaxf(bi1, bj1);
        float rb0 = fminf(bi2, bj2), rb1 = fminf(bi3, bj3);
        float w0 = fmaxf(__fsub_rn(rb0, lt0), 0.f), w1 = fmaxf(__fsub_rn(rb1, lt1), 0.f);
        float inter = __fmul_rn(w0, w1);
        float den = __fadd_rn(__fsub_rn(__fadd_rn(ai, area[oj]), inter), 1e-8f);
        float iou = __fdiv_rn(inter, den);
        s = iou > 0.5f;
    }
    u64 mask = __ballot(s);
    if (lane == 0) sup[(size_t)i * NW + w] = mask;
}

// ---------------- NMS scan: per-lane control-word replica, register prefetch ----------------
// Serial chain per box = bit-test -> cndmask -> and (pure VALU). The sup row's
// column l (this lane's keep word) and column c (the control word, lane-uniform)
// are prefetched 8 rows ahead into registers. One __shfl per 64-box chunk only.
__global__ __launch_bounds__(64) void k_nms3(
    const float* __restrict__ ssort, const u64* __restrict__ sup, u64* __restrict__ rem)
{
    int l = threadIdx.x;
    bool act = l < NW;
    u64 r = 0;
    if (act) {
        for (int b = 0; b < 64; ++b) {
            int idx = (l << 6) + b;
            if (idx < NBOX && ssort[idx] >= 0.05f) r |= (1ull << b);
        }
    }
    const int NG = NBOX / 8;   // 375 groups of 8 (3000 = 375*8 exactly)
    u64 sl_cur[8], sc_cur[8], sl_nxt[8], sc_nxt[8];
    #pragma unroll
    for (int k = 0; k < 8; ++k) {
        sl_cur[k] = act ? sup[(size_t)k * NW + l] : 0;
        sc_cur[k] = sup[(size_t)k * NW + (k >> 6)];
    }
    u64 wv = __shfl(r, 0);     // control word for chunk 0
    for (int g = 0; g < NG; ++g) {
        if (g + 1 < NG) {
            #pragma unroll
            for (int k = 0; k < 8; ++k) {
                int i = 8 * (g + 1) + k;
                sl_nxt[k] = act ? sup[(size_t)i * NW + l] : 0;
                sc_nxt[k] = sup[(size_t)i * NW + (i >> 6)];
            }
        }
        #pragma unroll
        for (int k = 0; k < 8; ++k) {
            int i = 8 * g + k;
            int b = i & 63;
            u64 on = (wv >> b) & 1ull;
            u64 ml = on ? sl_cur[k] : 0ull;
            u64 mc = on ? sc_cur[k] : 0ull;
            r &= ~ml;
            wv &= ~mc;
            if (b == 63) {                   // chunk boundary (uniform branch)
                int cn = (i >> 6) + 1;
                wv = __shfl(r, cn);          // fresh control word from owning lane
            }
        }
        #pragma unroll
        for (int k = 0; k < 8; ++k) { sl_cur[k] = sl_nxt[k]; sc_cur[k] = sc_nxt[k]; }
    }
    if (act) rem[l] = r;
}

// ---------------- final output assembly ----------------
__global__ __launch_bounds__(256) void k_out(
    const float* __restrict__ pr3, const float* __restrict__ pr4, const float* __restrict__ pr5,
    const float* __restrict__ classesF, const float* __restrict__ scores,
    const int* __restrict__ ord, const u64* __restrict__ rem, float* __restrict__ out)
{
    int t = blockIdx.x * 256 + threadIdx.x;
    if (t >= 21000) return;
    if (t < 12000) {
        int m = t >> 2, j = t & 3;
        int lvl = m / 1000, n = m - lvl * 1000;
        const float* pr = lvl == 0 ? pr3 : (lvl == 1 ? pr4 : pr5);
        out[t] = pr[n*4 + j];
    } else if (t < 15000) {
        out[t] = classesF[t - 12000];
    } else if (t < 18000) {
        out[t] = scores[t - 15000];
    } else {
        int p = t - 18000;
        int orig = ord[p];
        int bit = (int)((rem[p >> 6] >> (p & 63)) & 1ull);
        out[18000 + orig] = (float)bit;
    }
}

extern "C" void kernel_launch(void* const* d_in, const int* in_sizes, int n_in,
                              void* d_out, int out_size, void* d_ws, size_t ws_size,
                              hipStream_t stream)
{
    const float* p3  = (const float*)d_in[0];
    const float* p4  = (const float*)d_in[1];
    const float* p5  = (const float*)d_in[2];
    const float* pr3 = (const float*)d_in[3];
    const float* pr4 = (const float*)d_in[4];
    const float* pr5 = (const float*)d_in[5];
    const float* w1  = (const float*)d_in[6];
    const float* b1  = (const float*)d_in[7];
    const float* w2  = (const float*)d_in[8];
    const float* b2  = (const float*)d_in[9];
    const float* wc  = (const float*)d_in[10];
    const float* bc  = (const float*)d_in[11];

    float* ws    = (float*)d_ws;
    float* Cp    = ws + OFF_CP;
    float* fT3   = ws + OFF_FT3;
    float* fT4   = ws + OFF_FT4;
    float* fT5   = ws + OFF_FT5;
    f16*   Ah    = (f16*)(ws + OFF_AH);
    f16*   Al    = (f16*)(ws + OFF_AL);
    f16*   B1hT  = (f16*)(ws + OFF_B1HT);
    f16*   B1lT  = (f16*)(ws + OFF_B1LT);
    f16*   B2hT  = (f16*)(ws + OFF_B2HT);
    f16*   B2lT  = (f16*)(ws + OFF_B2LT);
    f16*   H1h   = (f16*)(ws + OFF_H1H);
    f16*   H1l   = (f16*)(ws + OFF_H1L);
    float* h2    = ws + OFF_H2;
    float* sc    = ws + OFF_SC;
    float* clf   = ws + OFF_CL;
    float* maxv  = ws + OFF_MAXV;
    float* obox  = ws + OFF_OBOX;
    float* area  = ws + OFF_AREA;
    int*   ord   = (int*)(ws + OFF_ORD);
    float* ssort = ws + OFF_SSORT;
    u64*   sup   = (u64*)(ws + OFF_SUP);
    u64*   rem   = (u64*)(ws + OFF_REM);
    float* wcT   = ws + OFF_WCT;
    float* out   = (float*)d_out;

    // ---- phase 1: prep (FT lives inside Cp space; dead before GEMM writes Cp) ----
    k_transpose2<<<dim3(256, 4), 256, 0, stream>>>(p3, fT3, 128 * 128);
    k_transpose2<<<dim3(64, 4),  256, 0, stream>>>(p4, fT4, 64 * 64);
    k_transpose2<<<dim3(16, 4),  256, 0, stream>>>(p5, fT5, 32 * 32);
    k_roialign2<<<dim3(NBOX, 7), 256, 0, stream>>>(fT3, fT4, fT5, pr3, pr4, pr5, Ah, Al);
    k_splitT<1><<<dim3(KDIM / 64, 16), 256, 0, stream>>>(w1, B1hT, B1lT, KDIM);
    k_splitT<0><<<dim3(16, 16), 256, 0, stream>>>(w2, B2hT, B2lT, 1024);

    // ---- phase 2: GEMMs (H1/H2 alias dead B1 region) ----
    k_gemm_mfma<3><<<dim3(24, 16, 3), 256, 0, stream>>>(Ah, Al, B1hT, B1lT, Cp, KDIM);
    k_reduce_split<3><<<3072, 256, 0, stream>>>(Cp, b1, H1h, H1l);
    k_gemm_mfma<3><<<dim3(24, 16, 3), 256, 0, stream>>>(H1h, H1l, B2hT, B2lT, Cp, 1024);
    k_reduce_f32<3><<<3072, 256, 0, stream>>>(Cp, b2, h2);

    // ---- phase 3: head + NMS (smalls alias dead B1lT region -> must run after GEMM1) ----
    k_wct<<<(NCLS * 1024 + 255) / 256, 256, 0, stream>>>(wc, wcT);
    k_boxmax<<<1, 1024, 0, stream>>>(pr3, pr4, pr5, maxv);
    k_head2<<<NBOX, 256, 0, stream>>>(h2, wcT, bc, sc, clf);
    k_prep<<<12, 256, 0, stream>>>(pr3, pr4, pr5, clf, maxv, obox, area);
    k_sort<<<1, 1024, 0, stream>>>(sc, ord, ssort);
    k_sup<<<dim3(NBOX, 12), 256, 0, stream>>>(ord, obox, area, sup);
    k_nms3<<<1, 64, 0, stream>>>(ssort, sup, rem);
    k_out<<<(21000 + 255) / 256, 256, 0, stream>>>(pr3, pr4, pr5, clf, sc, ord, rem, out);
}